// Round 6
// baseline (571.019 us; speedup 1.0000x reference)
//
#include <hip/hip_runtime.h>
#include <hip/hip_bf16.h>

// GATModel: 3-layer GAT (heads 4/4/1) + BN/ELU + residual + mean-pool + conv1d head.
// N=50000 nodes, E=800000 edges (+N self-loops handled analytically),
// NODE_DIM=HH=128, HID=32, HEADS=4, B=64 graphs.
//
// R5 changes vs R4 (gat_agg128 85us x2, bound by L2-miss gather path: 233MB
// fetch/dispatch, h table 25.6MB >> 4MB/XCD L2):
//  - h tables stored as bf16 (packed in GEMM epilogue from fp32 accumulators);
//    gather bytes/edge halve (512B->256B row). es/ed stay fp32 (computed
//    pre-rounding), so only the convex-combination inputs are rounded.
//  - edge chunk 8 -> 16 (bf16 halves in-flight register cost) => 2x MLP.
//  - layer-2 h table 6.4MB -> 3.2MB (near single-XCD L2 capacity).
//
// Workspace layout (~82.3 MB):
//   deg      [50000 i32]  @ 0
//   cursor   [50000 i32]  @ 208448
//   offs     [50001 i32]  @ 408448
//   es       [N*4 f32]    @ 608512
//   ed       [N*4 f32]    @ 1408512
//   csr_src  [800000 i32] @ 2208512
//   hbf      [N*128 bf16] @ 5408512   (layer2: N*32 bf16)
//   act0     [N*128 f32]  @ 31008512  (reused as h2 [N*32 f32] after free)
//   act1     [N*128 f32]  @ 56608512

#define NNODES 50000
#define NEDGES 800000
#define BN_INV 0.9999950000374997f  // 1/sqrt(1+1e-5)

__device__ __forceinline__ unsigned bf16rne(float f) {   // fp32 -> bf16 bits (RNE)
  unsigned u = __float_as_uint(f);
  return (u + 0x7fffu + ((u >> 16) & 1u)) >> 16;
}
__device__ __forceinline__ float bf_lo(unsigned u) { return __uint_as_float(u << 16); }
__device__ __forceinline__ float bf_hi(unsigned u) { return __uint_as_float(u & 0xffff0000u); }
__device__ __forceinline__ float bf_us(unsigned short s) { return __uint_as_float(((unsigned)s) << 16); }

// ---------------- CSR build ----------------

__global__ __launch_bounds__(256) void count_deg(const int* __restrict__ dst,
                                                 int* __restrict__ deg, int E) {
  int i = blockIdx.x * 256 + threadIdx.x;
  if (i < E) atomicAdd(&deg[dst[i]], 1);
}

__global__ __launch_bounds__(1024) void scan_kernel(const int* __restrict__ deg,
    int* __restrict__ offs, int* __restrict__ cursor, int Nn) {
  __shared__ int wsum[16];
  __shared__ int woff[17];
  __shared__ int carry;
  int t = threadIdx.x, lane = t & 63, w = t >> 6;
  if (t == 0) carry = 0;
  __syncthreads();
  for (int base = 0; base < Nn; base += 1024 * 8) {
    int v[8]; int s = 0;
    int i0 = base + t * 8;
#pragma unroll
    for (int j = 0; j < 8; ++j) { int i = i0 + j; v[j] = (i < Nn) ? deg[i] : 0; s += v[j]; }
    int incl = s;
#pragma unroll
    for (int o = 1; o < 64; o <<= 1) { int x = __shfl_up(incl, o); if (lane >= o) incl += x; }
    if (lane == 63) wsum[w] = incl;
    __syncthreads();
    if (t == 0) { int r = carry; for (int i = 0; i < 16; ++i) { woff[i] = r; r += wsum[i]; } woff[16] = r; }
    __syncthreads();
    int run = woff[w] + (incl - s);
#pragma unroll
    for (int j = 0; j < 8; ++j) {
      int i = i0 + j;
      if (i < Nn) { offs[i] = run; cursor[i] = run; }
      run += v[j];
    }
    __syncthreads();
    if (t == 0) carry = woff[16];
    __syncthreads();
  }
  if (t == 0) offs[Nn] = carry;
}

__global__ __launch_bounds__(256) void fill_csr(const int* __restrict__ src,
    const int* __restrict__ dst, int* __restrict__ cursor,
    int* __restrict__ csr, int E) {
  int i = blockIdx.x * 256 + threadIdx.x;
  if (i < E) {
    int d = dst[i];
    int pos = atomicAdd(&cursor[d], 1);
    csr[pos] = src[i];
  }
}

// --- GEMM: H(N x NC) = A(N x 128) @ W(128 x NC), fp32 acc, bf16 H, fused attn ---
// es/ed computed from fp32 accumulators (no bf16 error on attention coefs).

template <int NC, int NH>
__global__ __launch_bounds__(256) void gemm_attn(const float* __restrict__ A,
    const float* __restrict__ W, const float* __restrict__ a_s,
    const float* __restrict__ a_d, unsigned* __restrict__ Hbf,
    float* __restrict__ es, float* __restrict__ ed, int Nrows) {
  constexpr int CG = NC / 4;       // colgroups (4 cols each)
  constexpr int RG = 256 / CG;     // rowgroups
  constexpr int RPT = 32 / RG;     // rows per thread (block tile = 32 rows)
  int cg = threadIdx.x % CG;
  int rg = threadIdx.x / CG;
  int c0 = cg * 4;
  int rbase = blockIdx.x * 32 + rg * RPT;
  float acc[RPT][4];
#pragma unroll
  for (int r = 0; r < RPT; ++r)
#pragma unroll
    for (int j = 0; j < 4; ++j) acc[r][j] = 0.f;
  int rows[RPT];
#pragma unroll
  for (int r = 0; r < RPT; ++r) { int rr = rbase + r; rows[r] = rr < Nrows ? rr : Nrows - 1; }
#pragma unroll 8
  for (int k = 0; k < 128; k += 4) {
    float4 w0 = *(const float4*)&W[(k + 0) * NC + c0];
    float4 w1 = *(const float4*)&W[(k + 1) * NC + c0];
    float4 w2 = *(const float4*)&W[(k + 2) * NC + c0];
    float4 w3 = *(const float4*)&W[(k + 3) * NC + c0];
#pragma unroll
    for (int r = 0; r < RPT; ++r) {
      float4 a = *(const float4*)&A[(size_t)rows[r] * 128 + k];
      acc[r][0] += a.x * w0.x + a.y * w1.x + a.z * w2.x + a.w * w3.x;
      acc[r][1] += a.x * w0.y + a.y * w1.y + a.z * w2.y + a.w * w3.y;
      acc[r][2] += a.x * w0.z + a.y * w1.z + a.z * w2.z + a.w * w3.z;
      acc[r][3] += a.x * w0.w + a.y * w1.w + a.z * w2.w + a.w * w3.w;
    }
  }
  float4 as4 = *(const float4*)&a_s[c0];
  float4 ad4 = *(const float4*)&a_d[c0];
#pragma unroll
  for (int r = 0; r < RPT; ++r) {
    int rr = rbase + r;
    if (rr < Nrows) {
      uint2 p;
      p.x = bf16rne(acc[r][0]) | (bf16rne(acc[r][1]) << 16);
      p.y = bf16rne(acc[r][2]) | (bf16rne(acc[r][3]) << 16);
      *(uint2*)&Hbf[(size_t)rr * (NC / 2) + cg * 2] = p;
    }
    float ps = acc[r][0] * as4.x + acc[r][1] * as4.y + acc[r][2] * as4.z + acc[r][3] * as4.w;
    float pd = acc[r][0] * ad4.x + acc[r][1] * ad4.y + acc[r][2] * ad4.z + acc[r][3] * ad4.w;
#pragma unroll
    for (int o = 1; o < 8; o <<= 1) {
      ps += __shfl_xor(ps, o);
      pd += __shfl_xor(pd, o);
    }
    if ((cg & 7) == 0 && rr < Nrows) {
      int hh = cg >> 3;
      es[rr * NH + hh] = ps;
      ed[rr * NH + hh] = pd;
    }
  }
}

// --- GAT aggregation (HH=128, 4 heads), wave-per-node, 16-edge chunks, bf16 h ---
// Block = 256 = 4 waves = 4 nodes. Lane l owns channels {2l,2l+1} = one uint.

template <bool RES>
__global__ __launch_bounds__(256) void gat_agg128(const unsigned* __restrict__ hbf,
    const float* __restrict__ es, const float* __restrict__ ed,
    const int* __restrict__ offs, const int* __restrict__ csr,
    const float* __restrict__ bias, const float* __restrict__ gamma,
    const float* __restrict__ beta, const float* __restrict__ resid,
    float* __restrict__ out, int Nn) {
  constexpr int CH = 16;
  int n = blockIdx.x * 4 + (threadIdx.x >> 6);
  if (n >= Nn) return;
  int l = threadIdx.x & 63;
  int c0 = 2 * l;
  int hh = l >> 4;
  float edn = ed[n * 4 + hh];
  // self loop (softmax is shift-invariant; skip segment_max)
  float e0 = es[n * 4 + hh] + edn;
  e0 = e0 > 0.f ? e0 : 0.2f * e0;
  float w0 = __expf(e0);
  float den = w0;
  unsigned uself = hbf[(size_t)n * 64 + l];
  float accx = w0 * bf_lo(uself), accy = w0 * bf_hi(uself);
  int beg = offs[n], end = offs[n + 1];
  for (int base = beg; base < end; base += CH) {
    int cnt = end - base;  // >=1
    int s[CH];
#pragma unroll
    for (int j = 0; j < CH; ++j) s[j] = (j < cnt) ? csr[base + j] : n;
    unsigned u[CH];
#pragma unroll
    for (int j = 0; j < CH; ++j) u[j] = hbf[(size_t)s[j] * 64 + l];
    float w[CH];
#pragma unroll
    for (int j = 0; j < CH; ++j) {
      float e = es[s[j] * 4 + hh] + edn;
      e = e > 0.f ? e : 0.2f * e;
      w[j] = (j < cnt) ? __expf(e) : 0.f;
    }
#pragma unroll
    for (int j = 0; j < CH; ++j) {
      den += w[j];
      accx += w[j] * bf_lo(u[j]);
      accy += w[j] * bf_hi(u[j]);
    }
  }
  float inv = 1.0f / (den + 1e-16f);
  float2 bi = *(const float2*)&bias[c0];
  float2 ga = *(const float2*)&gamma[c0];
  float2 be = *(const float2*)&beta[c0];
  float vx = accx * inv + bi.x;
  float vy = accy * inv + bi.y;
  if (RES) {
    float2 rv = *(const float2*)&resid[(size_t)n * 128 + c0];
    vx += rv.x; vy += rv.y;
  }
  vx = ga.x * vx * BN_INV + be.x;
  vy = ga.y * vy * BN_INV + be.y;
  float2 o;
  o.x = vx > 0.f ? vx : __expf(vx) - 1.f;
  o.y = vy > 0.f ? vy : __expf(vy) - 1.f;
  *(float2*)&out[(size_t)n * 128 + c0] = o;
}

// --- layer-2 aggregation (H=1, O=32), 16-edge chunks, bf16 h, no atomics ---

__global__ __launch_bounds__(256) void gat_agg32(const unsigned short* __restrict__ hb,
    const float* __restrict__ es, const float* __restrict__ ed,
    const int* __restrict__ offs, const int* __restrict__ csr,
    const float* __restrict__ bias, float* __restrict__ h2, int Nn) {
  constexpr int CH = 16;
  int n = blockIdx.x * 8 + (threadIdx.x >> 5);
  if (n >= Nn) return;
  int c = threadIdx.x & 31;
  float edn = ed[n];
  float e0 = es[n] + edn;
  e0 = e0 > 0.f ? e0 : 0.2f * e0;
  float w0 = __expf(e0);
  float den = w0;
  float acc = w0 * bf_us(hb[(size_t)n * 32 + c]);
  int beg = offs[n], end = offs[n + 1];
  for (int base = beg; base < end; base += CH) {
    int cnt = end - base;
    int s[CH];
#pragma unroll
    for (int j = 0; j < CH; ++j) s[j] = (j < cnt) ? csr[base + j] : n;
    unsigned short u[CH];
#pragma unroll
    for (int j = 0; j < CH; ++j) u[j] = hb[(size_t)s[j] * 32 + c];
    float w[CH];
#pragma unroll
    for (int j = 0; j < CH; ++j) {
      float e = es[s[j]] + edn;
      e = e > 0.f ? e : 0.2f * e;
      w[j] = (j < cnt) ? __expf(e) : 0.f;
    }
#pragma unroll
    for (int j = 0; j < CH; ++j) {
      den += w[j];
      acc += w[j] * bf_us(u[j]);
    }
  }
  h2[(size_t)n * 32 + c] = acc / (den + 1e-16f) + bias[c];
}

// -------- head: mean-pool (sorted-batch range), conv1d x2, MLP, log_softmax ------

__global__ __launch_bounds__(256) void head_kernel(const float* __restrict__ h2,
    const int* __restrict__ batch,
    const float* __restrict__ c0w, const float* __restrict__ c0b,
    const float* __restrict__ cg0, const float* __restrict__ cb0,
    const float* __restrict__ c1w, const float* __restrict__ c1b,
    const float* __restrict__ l1w, const float* __restrict__ l1b,
    const float* __restrict__ l2w, const float* __restrict__ l2b,
    float* __restrict__ out) {
  int b = blockIdx.x;
  int t = threadIdx.x;
  __shared__ float sums[8][32];
  __shared__ float pooled[32];
  __shared__ float z1[32][32];
  __shared__ float z2[16][32];
  __shared__ float emb[16];
  __shared__ float hfc[8];
  __shared__ float logits[10];

  int lo = 0, hi = NNODES;
  while (lo < hi) { int mid = (lo + hi) >> 1; if (batch[mid] < b) lo = mid + 1; else hi = mid; }
  int start = lo;
  lo = 0; hi = NNODES;
  while (lo < hi) { int mid = (lo + hi) >> 1; if (batch[mid] < b + 1) lo = mid + 1; else hi = mid; }
  int end = lo;

  {
    int ch = t & 31, g = t >> 5;
    float s = 0.f;
    for (int i = start + g; i < end; i += 8) s += h2[(size_t)i * 32 + ch];
    sums[g][ch] = s;
  }
  __syncthreads();
  if (t < 32) {
    float s = 0.f;
#pragma unroll
    for (int g = 0; g < 8; ++g) s += sums[g][t];
    float cn = fmaxf((float)(end - start), 1.0f);
    pooled[t] = s / cn;
  }
  __syncthreads();
  for (int i = t; i < 1024; i += 256) {
    int oc = i >> 5, tt = i & 31;
    float a = c0b[oc];
#pragma unroll
    for (int k = 0; k < 5; ++k) {
      int p = tt + k - 2;
      if (p >= 0 && p < 32) a += pooled[p] * c0w[oc * 5 + k];
    }
    a = cg0[oc] * a * BN_INV + cb0[oc];
    z1[oc][tt] = a > 0.f ? a : __expf(a) - 1.f;
  }
  __syncthreads();
  for (int i = t; i < 512; i += 256) {
    int oc = i >> 5, tt = i & 31;
    float a = c1b[oc];
    for (int ic = 0; ic < 32; ++ic) {
      const float* wrow = &c1w[(oc * 32 + ic) * 5];
#pragma unroll
      for (int k = 0; k < 5; ++k) {
        int p = tt + k - 2;
        if (p >= 0 && p < 32) a += z1[ic][p] * wrow[k];
      }
    }
    z2[oc][tt] = a;
  }
  __syncthreads();
  if (t < 16) {
    float s = 0.f;
    for (int i = 0; i < 32; ++i) s += z2[t][i];
    s *= (1.0f / 32.0f);
    emb[t] = s;
    out[640 + b * 16 + t] = s;     // output 1: embed (64 x 16)
  }
  __syncthreads();
  if (t < 8) {
    float a = l1b[t];
    for (int i = 0; i < 16; ++i) a += emb[i] * l1w[i * 8 + t];
    hfc[t] = a > 0.f ? a : __expf(a) - 1.f;
  }
  __syncthreads();
  if (t < 10) {
    float a = l2b[t];
    for (int j = 0; j < 8; ++j) a += hfc[j] * l2w[j * 10 + t];
    logits[t] = a;
  }
  __syncthreads();
  if (t == 0) {
    float m = logits[0];
    for (int k = 1; k < 10; ++k) m = fmaxf(m, logits[k]);
    float s = 0.f;
    for (int k = 0; k < 10; ++k) s += __expf(logits[k] - m);
    float lse = m + logf(s);
    for (int k = 0; k < 10; ++k) out[b * 10 + k] = logits[k] - lse;  // output 0
  }
}

// ---------------- launch ----------------

extern "C" void kernel_launch(void* const* d_in, const int* in_sizes, int n_in,
                              void* d_out, int out_size, void* d_ws, size_t ws_size,
                              hipStream_t stream) {
  const float* x   = (const float*)d_in[0];
  const int* eidx  = (const int*)d_in[1];
  const int* esrc  = eidx;
  const int* edst  = eidx + NEDGES;
  const int* batch = (const int*)d_in[2];
  const float* W0  = (const float*)d_in[3];
  const float* a0s = (const float*)d_in[4];
  const float* a0d = (const float*)d_in[5];
  const float* b0  = (const float*)d_in[6];
  const float* W1  = (const float*)d_in[7];
  const float* a1s = (const float*)d_in[8];
  const float* a1d = (const float*)d_in[9];
  const float* b1  = (const float*)d_in[10];
  const float* W2  = (const float*)d_in[11];
  const float* a2s = (const float*)d_in[12];
  const float* a2d = (const float*)d_in[13];
  const float* b2  = (const float*)d_in[14];
  const float* g0  = (const float*)d_in[15];
  const float* be0 = (const float*)d_in[16];
  const float* g1  = (const float*)d_in[17];
  const float* be1 = (const float*)d_in[18];
  const float* c0w = (const float*)d_in[19];
  const float* c0b = (const float*)d_in[20];
  const float* cg0 = (const float*)d_in[21];
  const float* cb0 = (const float*)d_in[22];
  const float* c1w = (const float*)d_in[23];
  const float* c1b = (const float*)d_in[24];
  const float* l1w = (const float*)d_in[25];
  const float* l1b = (const float*)d_in[26];
  const float* l2w = (const float*)d_in[27];
  const float* l2b = (const float*)d_in[28];

  char* ws = (char*)d_ws;
  int*      deg    = (int*)(ws + 0);
  int*      cursor = (int*)(ws + 208448);
  int*      offs   = (int*)(ws + 408448);
  float*    es     = (float*)(ws + 608512);
  float*    ed     = (float*)(ws + 1408512);
  int*      csr    = (int*)(ws + 2208512);
  unsigned* hbf    = (unsigned*)(ws + 5408512);   // N x 64 uints (bf16 pairs)
  float*    act0   = (float*)(ws + 31008512);
  float*    act1   = (float*)(ws + 56608512);
  float*    h2     = act0;              // act0 free after layer-1 agg
  float*    out    = (float*)d_out;

  hipMemsetAsync(d_ws, 0, 200000, stream);

  count_deg<<<(NEDGES + 255) / 256, 256, 0, stream>>>(edst, deg, NEDGES);
  scan_kernel<<<1, 1024, 0, stream>>>(deg, offs, cursor, NNODES);
  fill_csr<<<(NEDGES + 255) / 256, 256, 0, stream>>>(esrc, edst, cursor, csr, NEDGES);

  const int gemm_grid = (NNODES + 31) / 32;

  // --- layer 0 ---
  gemm_attn<128, 4><<<gemm_grid, 256, 0, stream>>>(x, W0, a0s, a0d, hbf, es, ed, NNODES);
  gat_agg128<false><<<(NNODES + 3) / 4, 256, 0, stream>>>(hbf, es, ed, offs, csr, b0, g0, be0, nullptr, act0, NNODES);

  // --- layer 1 (residual) ---
  gemm_attn<128, 4><<<gemm_grid, 256, 0, stream>>>(act0, W1, a1s, a1d, hbf, es, ed, NNODES);
  gat_agg128<true><<<(NNODES + 3) / 4, 256, 0, stream>>>(hbf, es, ed, offs, csr, b1, g1, be1, act0, act1, NNODES);

  // --- layer 2 (H=1, O=32) ---
  gemm_attn<32, 1><<<gemm_grid, 256, 0, stream>>>(act1, W2, a2s, a2d, hbf, es, ed, NNODES);
  gat_agg32<<<(NNODES + 7) / 8, 256, 0, stream>>>((const unsigned short*)hbf, es, ed, offs, csr, b2, h2, NNODES);

  // --- head (pool fused) ---
  head_kernel<<<64, 256, 0, stream>>>(h2, batch, c0w, c0b, cg0, cb0,
                                      c1w, c1b, l1w, l1b, l2w, l2b, out);
}

// Round 7
// 442.380 us; speedup vs baseline: 1.2908x; 1.2908x over previous
//
#include <hip/hip_runtime.h>
#include <hip/hip_bf16.h>

// GATModel: 3-layer GAT (heads 4/4/1) + BN/ELU + residual + mean-pool + conv1d head.
// N=50000 nodes, E=800000 edges (+N self-loops handled analytically).
//
// R6 changes vs R5 (gemm_attn was 87us x3 = 46%: fp32 vector GEMM re-streaming
// 64KB W through L1/L2 every k-iter, 19 TFLOPS):
//  - GEMMs -> bf16 MFMA (16x16x32), W transposed+bf16 by a prep kernel, staged
//    in LDS (+8 bf16 row pad). fp32 accum, bf16 H out. ~10us each.
//  - es/ed via reassociation: es = A @ (W @ a_s). u-vectors precomputed once;
//    es/ed computed from fp32 activations (layer0: fused into x->bf16 convert;
//    layers1/2: fused into aggregation epilogue, values in registers).
//    => attention coefficients never see bf16 rounding of A@W output.
//  - agg epilogue also emits bf16 A-operand for next GEMM.
//
// Workspace (~58.3 MB): see offsets in kernel_launch.

#define NNODES 50000
#define NEDGES 800000
#define BN_INV 0.9999950000374997f  // 1/sqrt(1+1e-5)

typedef __attribute__((ext_vector_type(8))) short bf16x8;
typedef __attribute__((ext_vector_type(4))) float f32x4;

__device__ __forceinline__ unsigned bf16rne(float f) {   // fp32 -> bf16 bits (RNE)
  unsigned u = __float_as_uint(f);
  return (u + 0x7fffu + ((u >> 16) & 1u)) >> 16;
}
__device__ __forceinline__ float bf_lo(unsigned u) { return __uint_as_float(u << 16); }
__device__ __forceinline__ float bf_hi(unsigned u) { return __uint_as_float(u & 0xffff0000u); }
__device__ __forceinline__ float bf_us(unsigned short s) { return __uint_as_float(((unsigned)s) << 16); }

// ---------------- CSR build ----------------

__global__ __launch_bounds__(256) void count_deg(const int* __restrict__ dst,
                                                 int* __restrict__ deg, int E) {
  int i = blockIdx.x * 256 + threadIdx.x;
  if (i < E) atomicAdd(&deg[dst[i]], 1);
}

__global__ __launch_bounds__(1024) void scan_kernel(const int* __restrict__ deg,
    int* __restrict__ offs, int* __restrict__ cursor, int Nn) {
  __shared__ int wsum[16];
  __shared__ int woff[17];
  __shared__ int carry;
  int t = threadIdx.x, lane = t & 63, w = t >> 6;
  if (t == 0) carry = 0;
  __syncthreads();
  for (int base = 0; base < Nn; base += 1024 * 8) {
    int v[8]; int s = 0;
    int i0 = base + t * 8;
#pragma unroll
    for (int j = 0; j < 8; ++j) { int i = i0 + j; v[j] = (i < Nn) ? deg[i] : 0; s += v[j]; }
    int incl = s;
#pragma unroll
    for (int o = 1; o < 64; o <<= 1) { int x = __shfl_up(incl, o); if (lane >= o) incl += x; }
    if (lane == 63) wsum[w] = incl;
    __syncthreads();
    if (t == 0) { int r = carry; for (int i = 0; i < 16; ++i) { woff[i] = r; r += wsum[i]; } woff[16] = r; }
    __syncthreads();
    int run = woff[w] + (incl - s);
#pragma unroll
    for (int j = 0; j < 8; ++j) {
      int i = i0 + j;
      if (i < Nn) { offs[i] = run; cursor[i] = run; }
      run += v[j];
    }
    __syncthreads();
    if (t == 0) carry = woff[16];
    __syncthreads();
  }
  if (t == 0) offs[Nn] = carry;
}

__global__ __launch_bounds__(256) void fill_csr(const int* __restrict__ src,
    const int* __restrict__ dst, int* __restrict__ cursor,
    int* __restrict__ csr, int E) {
  int i = blockIdx.x * 256 + threadIdx.x;
  if (i < E) {
    int d = dst[i];
    int pos = atomicAdd(&cursor[d], 1);
    csr[pos] = src[i];
  }
}

// --------- prep: W0t/W1t/W2t (bf16, transposed) + u = W @ a_{s,d} vectors --------
// W?t[c*128+k] = bf16(W?[k*NC+c]).  u?s[k*NH+h] = sum_o W?[k*NC+h*32+o]*a?s[h*32+o].

__global__ __launch_bounds__(256) void prep_kernel(
    const float* __restrict__ W0, const float* __restrict__ W1, const float* __restrict__ W2,
    const float* __restrict__ a0s, const float* __restrict__ a0d,
    const float* __restrict__ a1s, const float* __restrict__ a1d,
    const float* __restrict__ a2s, const float* __restrict__ a2d,
    unsigned short* __restrict__ W0t, unsigned short* __restrict__ W1t,
    unsigned short* __restrict__ W2t,
    float* __restrict__ u0s, float* __restrict__ u0d,
    float* __restrict__ u1s, float* __restrict__ u1d,
    float* __restrict__ u2s, float* __restrict__ u2d) {
  int b = blockIdx.x, t = threadIdx.x;
  if (b < 64) {                       // W0t
    int idx = b * 256 + t; int c = idx >> 7, k = idx & 127;
    W0t[idx] = (unsigned short)bf16rne(W0[k * 128 + c]);
  } else if (b < 128) {               // W1t
    int idx = (b - 64) * 256 + t; int c = idx >> 7, k = idx & 127;
    W1t[idx] = (unsigned short)bf16rne(W1[k * 128 + c]);
  } else if (b < 144) {               // W2t (32 x 128)
    int idx = (b - 128) * 256 + t; int c = idx >> 7, k = idx & 127;
    W2t[idx] = (unsigned short)bf16rne(W2[k * 32 + c]);
  } else if (b == 144) {              // u0
    for (int it = 0; it < 4; ++it) {
      int idx = it * 256 + t;         // 0..1023
      int k = idx >> 3, rem = idx & 7, h = rem >> 1, sd = rem & 1;
      const float* av = sd ? a0d : a0s;
      float s = 0.f;
      for (int o = 0; o < 32; ++o) s += W0[k * 128 + h * 32 + o] * av[h * 32 + o];
      (sd ? u0d : u0s)[k * 4 + h] = s;
    }
  } else if (b == 145) {              // u1
    for (int it = 0; it < 4; ++it) {
      int idx = it * 256 + t;
      int k = idx >> 3, rem = idx & 7, h = rem >> 1, sd = rem & 1;
      const float* av = sd ? a1d : a1s;
      float s = 0.f;
      for (int o = 0; o < 32; ++o) s += W1[k * 128 + h * 32 + o] * av[h * 32 + o];
      (sd ? u1d : u1s)[k * 4 + h] = s;
    }
  } else {                            // u2 (256 outputs)
    int k = t >> 1, sd = t & 1;
    const float* av = sd ? a2d : a2s;
    float s = 0.f;
    for (int o = 0; o < 32; ++o) s += W2[k * 32 + o] * av[o];
    (sd ? u2d : u2s)[k] = s;
  }
}

// --------- xprep: x(f32) -> xbf(bf16) + es0/ed0 = x . u0 (one wave per node) -----

__global__ __launch_bounds__(256) void xprep_kernel(const float* __restrict__ x,
    unsigned* __restrict__ xbf, const float* __restrict__ u0s,
    const float* __restrict__ u0d, float* __restrict__ es, float* __restrict__ ed,
    int Nn) {
  int n = blockIdx.x * 4 + (threadIdx.x >> 6);
  if (n >= Nn) return;
  int l = threadIdx.x & 63;
  int c0 = 2 * l;
  float2 v = *(const float2*)&x[(size_t)n * 128 + c0];
  xbf[(size_t)n * 64 + l] = bf16rne(v.x) | (bf16rne(v.y) << 16);
  float ps[4], pd[4];
#pragma unroll
  for (int h = 0; h < 4; ++h) {
    ps[h] = v.x * u0s[c0 * 4 + h] + v.y * u0s[(c0 + 1) * 4 + h];
    pd[h] = v.x * u0d[c0 * 4 + h] + v.y * u0d[(c0 + 1) * 4 + h];
  }
#pragma unroll
  for (int h = 0; h < 4; ++h)
#pragma unroll
    for (int o = 32; o; o >>= 1) { ps[h] += __shfl_xor(ps[h], o); pd[h] += __shfl_xor(pd[h], o); }
  if (l == 0) {
#pragma unroll
    for (int h = 0; h < 4; ++h) { es[n * 4 + h] = ps[h]; ed[n * 4 + h] = pd[h]; }
  }
}

// --------- MFMA GEMM: H(N x NC, bf16) = A(N x 128, bf16) @ W(128 x NC, bf16) -----
// Block 256 = 4 waves, 64 rows. Wt (transposed W) staged in LDS with +8 pad.
// 16x16x32 MFMA; A slot (g,j) = A[row][kk*32+8g+j], B slot = W[kk*32+8g+j][col]
// (identical slot->k maps for A and B => contraction exact for any HW k-perm).
// C/D: row = 4*(lane>>4)+reg, col = lane&15  [HW-verified layout].

template <int NC>
__global__ __launch_bounds__(256) void gemm_mfma(const unsigned short* __restrict__ Abf,
    const unsigned short* __restrict__ Wt, unsigned short* __restrict__ Hbf,
    int Nrows) {
  constexpr int NT = NC / 16;
  __shared__ unsigned short lw[NC][136];
  int tid = threadIdx.x;
  for (int idx = tid; idx < NC * 16; idx += 256) {
    int c = idx >> 4, k0 = (idx & 15) * 8;
    *(uint4*)&lw[c][k0] = *(const uint4*)&Wt[c * 128 + k0];
  }
  __syncthreads();
  int w = tid >> 6, l = tid & 63;
  int g = l >> 4, i = l & 15;
  int rbase = blockIdx.x * 64 + w * 16;
  int arow = rbase + i; arow = arow < Nrows ? arow : Nrows - 1;
  bf16x8 a[4];
#pragma unroll
  for (int kk = 0; kk < 4; ++kk)
    a[kk] = *(const bf16x8*)&Abf[(size_t)arow * 128 + kk * 32 + g * 8];
  f32x4 acc[NT];
#pragma unroll
  for (int t = 0; t < NT; ++t) acc[t] = (f32x4){0.f, 0.f, 0.f, 0.f};
#pragma unroll
  for (int kk = 0; kk < 4; ++kk) {
#pragma unroll
    for (int t = 0; t < NT; ++t) {
      bf16x8 b = *(const bf16x8*)&lw[t * 16 + i][kk * 32 + g * 8];
      acc[t] = __builtin_amdgcn_mfma_f32_16x16x32_bf16(a[kk], b, acc[t], 0, 0, 0);
    }
  }
  int crow0 = rbase + g * 4;
#pragma unroll
  for (int t = 0; t < NT; ++t)
#pragma unroll
    for (int r = 0; r < 4; ++r) {
      int row = crow0 + r;
      if (row < Nrows)
        Hbf[(size_t)row * NC + t * 16 + i] = (unsigned short)bf16rne(acc[t][r]);
    }
}

// --- GAT aggregation (HH=128, 4 heads), wave-per-node, 16-edge chunks, bf16 h ---
// Epilogue: f32 act (optional), bf16 A for next GEMM, next-layer es/ed via u.

template <bool RES, bool WRITE_F32, int NEXT_NH>
__global__ __launch_bounds__(256) void gat_agg128(const unsigned* __restrict__ hbf,
    const float* __restrict__ es, const float* __restrict__ ed,
    const int* __restrict__ offs, const int* __restrict__ csr,
    const float* __restrict__ bias, const float* __restrict__ gamma,
    const float* __restrict__ beta, const float* __restrict__ resid,
    float* __restrict__ out_f32, unsigned* __restrict__ out_bf,
    const float* __restrict__ uns, const float* __restrict__ und,
    float* __restrict__ es_next, float* __restrict__ ed_next, int Nn) {
  constexpr int CHK = 16;
  int n = blockIdx.x * 4 + (threadIdx.x >> 6);
  if (n >= Nn) return;
  int l = threadIdx.x & 63;
  int c0 = 2 * l;
  int hh = l >> 4;
  float edn = ed[n * 4 + hh];
  float e0 = es[n * 4 + hh] + edn;   // self loop; softmax shift-invariant
  e0 = e0 > 0.f ? e0 : 0.2f * e0;
  float w0 = __expf(e0);
  float den = w0;
  unsigned uself = hbf[(size_t)n * 64 + l];
  float accx = w0 * bf_lo(uself), accy = w0 * bf_hi(uself);
  int beg = offs[n], end = offs[n + 1];
  for (int base = beg; base < end; base += CHK) {
    int cnt = end - base;
    int s[CHK];
#pragma unroll
    for (int j = 0; j < CHK; ++j) s[j] = (j < cnt) ? csr[base + j] : n;
    unsigned u[CHK];
#pragma unroll
    for (int j = 0; j < CHK; ++j) u[j] = hbf[(size_t)s[j] * 64 + l];
    float w[CHK];
#pragma unroll
    for (int j = 0; j < CHK; ++j) {
      float e = es[s[j] * 4 + hh] + edn;
      e = e > 0.f ? e : 0.2f * e;
      w[j] = (j < cnt) ? __expf(e) : 0.f;
    }
#pragma unroll
    for (int j = 0; j < CHK; ++j) {
      den += w[j];
      accx += w[j] * bf_lo(u[j]);
      accy += w[j] * bf_hi(u[j]);
    }
  }
  float inv = 1.0f / (den + 1e-16f);
  float2 bi = *(const float2*)&bias[c0];
  float2 ga = *(const float2*)&gamma[c0];
  float2 be = *(const float2*)&beta[c0];
  float vx = accx * inv + bi.x;
  float vy = accy * inv + bi.y;
  if (RES) {
    float2 rv = *(const float2*)&resid[(size_t)n * 128 + c0];
    vx += rv.x; vy += rv.y;
  }
  vx = ga.x * vx * BN_INV + be.x;
  vy = ga.y * vy * BN_INV + be.y;
  float ox = vx > 0.f ? vx : __expf(vx) - 1.f;
  float oy = vy > 0.f ? vy : __expf(vy) - 1.f;
  if (WRITE_F32) *(float2*)&out_f32[(size_t)n * 128 + c0] = make_float2(ox, oy);
  out_bf[(size_t)n * 64 + l] = bf16rne(ox) | (bf16rne(oy) << 16);
  // next-layer attention coefficients: es_next = act . u
  float ps[NEXT_NH], pd[NEXT_NH];
#pragma unroll
  for (int h = 0; h < NEXT_NH; ++h) {
    ps[h] = ox * uns[c0 * NEXT_NH + h] + oy * uns[(c0 + 1) * NEXT_NH + h];
    pd[h] = ox * und[c0 * NEXT_NH + h] + oy * und[(c0 + 1) * NEXT_NH + h];
  }
#pragma unroll
  for (int h = 0; h < NEXT_NH; ++h)
#pragma unroll
    for (int o = 32; o; o >>= 1) { ps[h] += __shfl_xor(ps[h], o); pd[h] += __shfl_xor(pd[h], o); }
  if (l == 0) {
#pragma unroll
    for (int h = 0; h < NEXT_NH; ++h) {
      es_next[n * NEXT_NH + h] = ps[h];
      ed_next[n * NEXT_NH + h] = pd[h];
    }
  }
}

// --- layer-2 aggregation (H=1, O=32), 16-edge chunks, bf16 h, no atomics ---

__global__ __launch_bounds__(256) void gat_agg32(const unsigned short* __restrict__ hb,
    const float* __restrict__ es, const float* __restrict__ ed,
    const int* __restrict__ offs, const int* __restrict__ csr,
    const float* __restrict__ bias, float* __restrict__ h2, int Nn) {
  constexpr int CHK = 16;
  int n = blockIdx.x * 8 + (threadIdx.x >> 5);
  if (n >= Nn) return;
  int c = threadIdx.x & 31;
  float edn = ed[n];
  float e0 = es[n] + edn;
  e0 = e0 > 0.f ? e0 : 0.2f * e0;
  float w0 = __expf(e0);
  float den = w0;
  float acc = w0 * bf_us(hb[(size_t)n * 32 + c]);
  int beg = offs[n], end = offs[n + 1];
  for (int base = beg; base < end; base += CHK) {
    int cnt = end - base;
    int s[CHK];
#pragma unroll
    for (int j = 0; j < CHK; ++j) s[j] = (j < cnt) ? csr[base + j] : n;
    unsigned short u[CHK];
#pragma unroll
    for (int j = 0; j < CHK; ++j) u[j] = hb[(size_t)s[j] * 32 + c];
    float w[CHK];
#pragma unroll
    for (int j = 0; j < CHK; ++j) {
      float e = es[s[j]] + edn;
      e = e > 0.f ? e : 0.2f * e;
      w[j] = (j < cnt) ? __expf(e) : 0.f;
    }
#pragma unroll
    for (int j = 0; j < CHK; ++j) {
      den += w[j];
      acc += w[j] * bf_us(u[j]);
    }
  }
  h2[(size_t)n * 32 + c] = acc / (den + 1e-16f) + bias[c];
}

// -------- head: mean-pool (sorted-batch range), conv1d x2, MLP, log_softmax ------

__global__ __launch_bounds__(256) void head_kernel(const float* __restrict__ h2,
    const int* __restrict__ batch,
    const float* __restrict__ c0w, const float* __restrict__ c0b,
    const float* __restrict__ cg0, const float* __restrict__ cb0,
    const float* __restrict__ c1w, const float* __restrict__ c1b,
    const float* __restrict__ l1w, const float* __restrict__ l1b,
    const float* __restrict__ l2w, const float* __restrict__ l2b,
    float* __restrict__ out) {
  int b = blockIdx.x;
  int t = threadIdx.x;
  __shared__ float sums[8][32];
  __shared__ float pooled[32];
  __shared__ float z1[32][32];
  __shared__ float z2[16][32];
  __shared__ float emb[16];
  __shared__ float hfc[8];
  __shared__ float logits[10];

  int lo = 0, hi = NNODES;
  while (lo < hi) { int mid = (lo + hi) >> 1; if (batch[mid] < b) lo = mid + 1; else hi = mid; }
  int start = lo;
  lo = 0; hi = NNODES;
  while (lo < hi) { int mid = (lo + hi) >> 1; if (batch[mid] < b + 1) lo = mid + 1; else hi = mid; }
  int end = lo;

  {
    int ch = t & 31, g = t >> 5;
    float s = 0.f;
    for (int i = start + g; i < end; i += 8) s += h2[(size_t)i * 32 + ch];
    sums[g][ch] = s;
  }
  __syncthreads();
  if (t < 32) {
    float s = 0.f;
#pragma unroll
    for (int g = 0; g < 8; ++g) s += sums[g][t];
    float cn = fmaxf((float)(end - start), 1.0f);
    pooled[t] = s / cn;
  }
  __syncthreads();
  for (int i = t; i < 1024; i += 256) {
    int oc = i >> 5, tt = i & 31;
    float a = c0b[oc];
#pragma unroll
    for (int k = 0; k < 5; ++k) {
      int p = tt + k - 2;
      if (p >= 0 && p < 32) a += pooled[p] * c0w[oc * 5 + k];
    }
    a = cg0[oc] * a * BN_INV + cb0[oc];
    z1[oc][tt] = a > 0.f ? a : __expf(a) - 1.f;
  }
  __syncthreads();
  for (int i = t; i < 512; i += 256) {
    int oc = i >> 5, tt = i & 31;
    float a = c1b[oc];
    for (int ic = 0; ic < 32; ++ic) {
      const float* wrow = &c1w[(oc * 32 + ic) * 5];
#pragma unroll
      for (int k = 0; k < 5; ++k) {
        int p = tt + k - 2;
        if (p >= 0 && p < 32) a += z1[ic][p] * wrow[k];
      }
    }
    z2[oc][tt] = a;
  }
  __syncthreads();
  if (t < 16) {
    float s = 0.f;
    for (int i = 0; i < 32; ++i) s += z2[t][i];
    s *= (1.0f / 32.0f);
    emb[t] = s;
    out[640 + b * 16 + t] = s;     // output 1: embed (64 x 16)
  }
  __syncthreads();
  if (t < 8) {
    float a = l1b[t];
    for (int i = 0; i < 16; ++i) a += emb[i] * l1w[i * 8 + t];
    hfc[t] = a > 0.f ? a : __expf(a) - 1.f;
  }
  __syncthreads();
  if (t < 10) {
    float a = l2b[t];
    for (int j = 0; j < 8; ++j) a += hfc[j] * l2w[j * 10 + t];
    logits[t] = a;
  }
  __syncthreads();
  if (t == 0) {
    float m = logits[0];
    for (int k = 1; k < 10; ++k) m = fmaxf(m, logits[k]);
    float s = 0.f;
    for (int k = 0; k < 10; ++k) s += __expf(logits[k] - m);
    float lse = m + logf(s);
    for (int k = 0; k < 10; ++k) out[b * 10 + k] = logits[k] - lse;  // output 0
  }
}

// ---------------- launch ----------------

extern "C" void kernel_launch(void* const* d_in, const int* in_sizes, int n_in,
                              void* d_out, int out_size, void* d_ws, size_t ws_size,
                              hipStream_t stream) {
  const float* x   = (const float*)d_in[0];
  const int* eidx  = (const int*)d_in[1];
  const int* esrc  = eidx;
  const int* edst  = eidx + NEDGES;
  const int* batch = (const int*)d_in[2];
  const float* W0  = (const float*)d_in[3];
  const float* a0s = (const float*)d_in[4];
  const float* a0d = (const float*)d_in[5];
  const float* b0  = (const float*)d_in[6];
  const float* W1  = (const float*)d_in[7];
  const float* a1s = (const float*)d_in[8];
  const float* a1d = (const float*)d_in[9];
  const float* b1  = (const float*)d_in[10];
  const float* W2  = (const float*)d_in[11];
  const float* a2s = (const float*)d_in[12];
  const float* a2d = (const float*)d_in[13];
  const float* b2  = (const float*)d_in[14];
  const float* g0  = (const float*)d_in[15];
  const float* be0 = (const float*)d_in[16];
  const float* g1  = (const float*)d_in[17];
  const float* be1 = (const float*)d_in[18];
  const float* c0w = (const float*)d_in[19];
  const float* c0b = (const float*)d_in[20];
  const float* cg0 = (const float*)d_in[21];
  const float* cb0 = (const float*)d_in[22];
  const float* c1w = (const float*)d_in[23];
  const float* c1b = (const float*)d_in[24];
  const float* l1w = (const float*)d_in[25];
  const float* l1b = (const float*)d_in[26];
  const float* l2w = (const float*)d_in[27];
  const float* l2b = (const float*)d_in[28];

  char* ws = (char*)d_ws;
  int*            deg    = (int*)(ws + 0);
  int*            cursor = (int*)(ws + 208448);
  int*            offs   = (int*)(ws + 408448);
  float*          esA    = (float*)(ws + 608512);
  float*          edA    = (float*)(ws + 1408512);
  float*          esB    = (float*)(ws + 2208512);
  float*          edB    = (float*)(ws + 3008512);
  int*            csr    = (int*)(ws + 3808512);
  unsigned*       Abf    = (unsigned*)(ws + 7008512);    // N x 64 uints (bf16 pairs)
  unsigned*       hbf    = (unsigned*)(ws + 19808512);   // N x 64 uints
  float*          act0   = (float*)(ws + 32608512);      // N x 128 f32 (h2 reuse)
  unsigned short* W0t    = (unsigned short*)(ws + 58208512);
  unsigned short* W1t    = (unsigned short*)(ws + 58241280);
  unsigned short* W2t    = (unsigned short*)(ws + 58274048);
  float*          u0s    = (float*)(ws + 58282240);
  float*          u0d    = (float*)(ws + 58284288);
  float*          u1s    = (float*)(ws + 58286336);
  float*          u1d    = (float*)(ws + 58288384);
  float*          u2s    = (float*)(ws + 58290432);
  float*          u2d    = (float*)(ws + 58290944);
  float*          h2     = act0;
  float*          out    = (float*)d_out;

  hipMemsetAsync(d_ws, 0, 200000, stream);   // deg = 0

  count_deg<<<(NEDGES + 255) / 256, 256, 0, stream>>>(edst, deg, NEDGES);
  scan_kernel<<<1, 1024, 0, stream>>>(deg, offs, cursor, NNODES);
  fill_csr<<<(NEDGES + 255) / 256, 256, 0, stream>>>(esrc, edst, cursor, csr, NEDGES);

  prep_kernel<<<147, 256, 0, stream>>>(W0, W1, W2, a0s, a0d, a1s, a1d, a2s, a2d,
                                       W0t, W1t, W2t, u0s, u0d, u1s, u1d, u2s, u2d);
  xprep_kernel<<<NNODES / 4, 256, 0, stream>>>(x, Abf, u0s, u0d, esA, edA, NNODES);

  const int ggrid = (NNODES + 63) / 64;

  // --- layer 0 ---
  gemm_mfma<128><<<ggrid, 256, 0, stream>>>((const unsigned short*)Abf, W0t,
                                            (unsigned short*)hbf, NNODES);
  gat_agg128<false, true, 4><<<(NNODES + 3) / 4, 256, 0, stream>>>(
      hbf, esA, edA, offs, csr, b0, g0, be0, nullptr,
      act0, Abf, u1s, u1d, esB, edB, NNODES);

  // --- layer 1 (residual) ---
  gemm_mfma<128><<<ggrid, 256, 0, stream>>>((const unsigned short*)Abf, W1t,
                                            (unsigned short*)hbf, NNODES);
  gat_agg128<true, false, 1><<<(NNODES + 3) / 4, 256, 0, stream>>>(
      hbf, esB, edB, offs, csr, b1, g1, be1, act0,
      nullptr, Abf, u2s, u2d, esA, edA, NNODES);

  // --- layer 2 (H=1, O=32) ---
  gemm_mfma<32><<<ggrid, 256, 0, stream>>>((const unsigned short*)Abf, W2t,
                                           (unsigned short*)hbf, NNODES);
  gat_agg32<<<(NNODES + 7) / 8, 256, 0, stream>>>((const unsigned short*)hbf,
                                                  esA, edA, offs, csr, b2, h2, NNODES);

  // --- head (pool fused) ---
  head_kernel<<<64, 256, 0, stream>>>(h2, batch, c0w, c0b, cg0, cb0,
                                      c1w, c1b, l1w, l1b, l2w, l2b, out);
}

// Round 8
// 402.152 us; speedup vs baseline: 1.4199x; 1.1000x over previous
//
#include <hip/hip_runtime.h>
#include <hip/hip_bf16.h>

// GATModel: 3-layer GAT (heads 4/4/1) + BN/ELU + residual + mean-pool + conv1d head.
// N=50000 nodes, E=800000 edges (+N self-loops handled analytically).
//
// R7 changes vs R6 (gat_agg128 80us x2 = 36%, VALU-overhead-bound: 54% VALUBusy
// = ~15 wave-instrs/edge replicated across 64 lanes serving ONE node):
//  - gat_agg128/gat_agg32 restructured to 16 lanes/node (lane = 8 channels via
//    uint4 of bf16), 4 nodes per wave: per-edge scalar overhead (csr/es loads,
//    leaky, exp, pad-select, addressing) amortized 4x per wave-instruction.
//    exp redundancy 16x -> 4x. Chunk 8 edges (8 uint4 gathers in flight/lane).
//  - epilogues rewritten for 16-lane groups (shfl_xor 1/2/4/8 reductions).
//
// Workspace (~58.3 MB): see offsets in kernel_launch.

#define NNODES 50000
#define NEDGES 800000
#define BN_INV 0.9999950000374997f  // 1/sqrt(1+1e-5)

typedef __attribute__((ext_vector_type(8))) short bf16x8;
typedef __attribute__((ext_vector_type(4))) float f32x4;

__device__ __forceinline__ unsigned bf16rne(float f) {   // fp32 -> bf16 bits (RNE)
  unsigned u = __float_as_uint(f);
  return (u + 0x7fffu + ((u >> 16) & 1u)) >> 16;
}
__device__ __forceinline__ float bf_lo(unsigned u) { return __uint_as_float(u << 16); }
__device__ __forceinline__ float bf_hi(unsigned u) { return __uint_as_float(u & 0xffff0000u); }
__device__ __forceinline__ float bf_us(unsigned short s) { return __uint_as_float(((unsigned)s) << 16); }

// ---------------- CSR build ----------------

__global__ __launch_bounds__(256) void count_deg(const int* __restrict__ dst,
                                                 int* __restrict__ deg, int E) {
  int i = blockIdx.x * 256 + threadIdx.x;
  if (i < E) atomicAdd(&deg[dst[i]], 1);
}

__global__ __launch_bounds__(1024) void scan_kernel(const int* __restrict__ deg,
    int* __restrict__ offs, int* __restrict__ cursor, int Nn) {
  __shared__ int wsum[16];
  __shared__ int woff[17];
  __shared__ int carry;
  int t = threadIdx.x, lane = t & 63, w = t >> 6;
  if (t == 0) carry = 0;
  __syncthreads();
  for (int base = 0; base < Nn; base += 1024 * 8) {
    int v[8]; int s = 0;
    int i0 = base + t * 8;
#pragma unroll
    for (int j = 0; j < 8; ++j) { int i = i0 + j; v[j] = (i < Nn) ? deg[i] : 0; s += v[j]; }
    int incl = s;
#pragma unroll
    for (int o = 1; o < 64; o <<= 1) { int x = __shfl_up(incl, o); if (lane >= o) incl += x; }
    if (lane == 63) wsum[w] = incl;
    __syncthreads();
    if (t == 0) { int r = carry; for (int i = 0; i < 16; ++i) { woff[i] = r; r += wsum[i]; } woff[16] = r; }
    __syncthreads();
    int run = woff[w] + (incl - s);
#pragma unroll
    for (int j = 0; j < 8; ++j) {
      int i = i0 + j;
      if (i < Nn) { offs[i] = run; cursor[i] = run; }
      run += v[j];
    }
    __syncthreads();
    if (t == 0) carry = woff[16];
    __syncthreads();
  }
  if (t == 0) offs[Nn] = carry;
}

__global__ __launch_bounds__(256) void fill_csr(const int* __restrict__ src,
    const int* __restrict__ dst, int* __restrict__ cursor,
    int* __restrict__ csr, int E) {
  int i = blockIdx.x * 256 + threadIdx.x;
  if (i < E) {
    int d = dst[i];
    int pos = atomicAdd(&cursor[d], 1);
    csr[pos] = src[i];
  }
}

// --------- prep: W0t/W1t/W2t (bf16, transposed) + u = W @ a_{s,d} vectors --------

__global__ __launch_bounds__(256) void prep_kernel(
    const float* __restrict__ W0, const float* __restrict__ W1, const float* __restrict__ W2,
    const float* __restrict__ a0s, const float* __restrict__ a0d,
    const float* __restrict__ a1s, const float* __restrict__ a1d,
    const float* __restrict__ a2s, const float* __restrict__ a2d,
    unsigned short* __restrict__ W0t, unsigned short* __restrict__ W1t,
    unsigned short* __restrict__ W2t,
    float* __restrict__ u0s, float* __restrict__ u0d,
    float* __restrict__ u1s, float* __restrict__ u1d,
    float* __restrict__ u2s, float* __restrict__ u2d) {
  int b = blockIdx.x, t = threadIdx.x;
  if (b < 64) {                       // W0t
    int idx = b * 256 + t; int c = idx >> 7, k = idx & 127;
    W0t[idx] = (unsigned short)bf16rne(W0[k * 128 + c]);
  } else if (b < 128) {               // W1t
    int idx = (b - 64) * 256 + t; int c = idx >> 7, k = idx & 127;
    W1t[idx] = (unsigned short)bf16rne(W1[k * 128 + c]);
  } else if (b < 144) {               // W2t (32 x 128)
    int idx = (b - 128) * 256 + t; int c = idx >> 7, k = idx & 127;
    W2t[idx] = (unsigned short)bf16rne(W2[k * 32 + c]);
  } else if (b == 144) {              // u0
    for (int it = 0; it < 4; ++it) {
      int idx = it * 256 + t;         // 0..1023
      int k = idx >> 3, rem = idx & 7, h = rem >> 1, sd = rem & 1;
      const float* av = sd ? a0d : a0s;
      float s = 0.f;
      for (int o = 0; o < 32; ++o) s += W0[k * 128 + h * 32 + o] * av[h * 32 + o];
      (sd ? u0d : u0s)[k * 4 + h] = s;
    }
  } else if (b == 145) {              // u1
    for (int it = 0; it < 4; ++it) {
      int idx = it * 256 + t;
      int k = idx >> 3, rem = idx & 7, h = rem >> 1, sd = rem & 1;
      const float* av = sd ? a1d : a1s;
      float s = 0.f;
      for (int o = 0; o < 32; ++o) s += W1[k * 128 + h * 32 + o] * av[h * 32 + o];
      (sd ? u1d : u1s)[k * 4 + h] = s;
    }
  } else {                            // u2 (256 outputs)
    int k = t >> 1, sd = t & 1;
    const float* av = sd ? a2d : a2s;
    float s = 0.f;
    for (int o = 0; o < 32; ++o) s += W2[k * 32 + o] * av[o];
    (sd ? u2d : u2s)[k] = s;
  }
}

// --------- xprep: x(f32) -> xbf(bf16) + es0/ed0 = x . u0 (one wave per node) -----

__global__ __launch_bounds__(256) void xprep_kernel(const float* __restrict__ x,
    unsigned* __restrict__ xbf, const float* __restrict__ u0s,
    const float* __restrict__ u0d, float* __restrict__ es, float* __restrict__ ed,
    int Nn) {
  int n = blockIdx.x * 4 + (threadIdx.x >> 6);
  if (n >= Nn) return;
  int l = threadIdx.x & 63;
  int c0 = 2 * l;
  float2 v = *(const float2*)&x[(size_t)n * 128 + c0];
  xbf[(size_t)n * 64 + l] = bf16rne(v.x) | (bf16rne(v.y) << 16);
  float ps[4], pd[4];
#pragma unroll
  for (int h = 0; h < 4; ++h) {
    ps[h] = v.x * u0s[c0 * 4 + h] + v.y * u0s[(c0 + 1) * 4 + h];
    pd[h] = v.x * u0d[c0 * 4 + h] + v.y * u0d[(c0 + 1) * 4 + h];
  }
#pragma unroll
  for (int h = 0; h < 4; ++h)
#pragma unroll
    for (int o = 32; o; o >>= 1) { ps[h] += __shfl_xor(ps[h], o); pd[h] += __shfl_xor(pd[h], o); }
  if (l == 0) {
#pragma unroll
    for (int h = 0; h < 4; ++h) { es[n * 4 + h] = ps[h]; ed[n * 4 + h] = pd[h]; }
  }
}

// --------- MFMA GEMM: H(N x NC, bf16) = A(N x 128, bf16) @ W(128 x NC, bf16) -----

template <int NC>
__global__ __launch_bounds__(256) void gemm_mfma(const unsigned short* __restrict__ Abf,
    const unsigned short* __restrict__ Wt, unsigned short* __restrict__ Hbf,
    int Nrows) {
  constexpr int NT = NC / 16;
  __shared__ unsigned short lw[NC][136];
  int tid = threadIdx.x;
  for (int idx = tid; idx < NC * 16; idx += 256) {
    int c = idx >> 4, k0 = (idx & 15) * 8;
    *(uint4*)&lw[c][k0] = *(const uint4*)&Wt[c * 128 + k0];
  }
  __syncthreads();
  int w = tid >> 6, l = tid & 63;
  int g = l >> 4, i = l & 15;
  int rbase = blockIdx.x * 64 + w * 16;
  int arow = rbase + i; arow = arow < Nrows ? arow : Nrows - 1;
  bf16x8 a[4];
#pragma unroll
  for (int kk = 0; kk < 4; ++kk)
    a[kk] = *(const bf16x8*)&Abf[(size_t)arow * 128 + kk * 32 + g * 8];
  f32x4 acc[NT];
#pragma unroll
  for (int t = 0; t < NT; ++t) acc[t] = (f32x4){0.f, 0.f, 0.f, 0.f};
#pragma unroll
  for (int kk = 0; kk < 4; ++kk) {
#pragma unroll
    for (int t = 0; t < NT; ++t) {
      bf16x8 b = *(const bf16x8*)&lw[t * 16 + i][kk * 32 + g * 8];
      acc[t] = __builtin_amdgcn_mfma_f32_16x16x32_bf16(a[kk], b, acc[t], 0, 0, 0);
    }
  }
  int crow0 = rbase + g * 4;
#pragma unroll
  for (int t = 0; t < NT; ++t)
#pragma unroll
    for (int r = 0; r < 4; ++r) {
      int row = crow0 + r;
      if (row < Nrows)
        Hbf[(size_t)row * NC + t * 16 + i] = (unsigned short)bf16rne(acc[t][r]);
    }
}

// --- GAT aggregation (HH=128, 4 heads): 16 lanes/node, 4 nodes/wave, bf16 h ---
// Lane q (= l&15) owns channels [8q, 8q+8) = one uint4 of bf16. head = q>>2.
// Epilogue: f32 act (optional), bf16 A for next GEMM, next-layer es/ed via u.

template <bool RES, bool WRITE_F32, int NEXT_NH>
__global__ __launch_bounds__(256) void gat_agg128(const uint4* __restrict__ hbf,
    const float* __restrict__ es, const float* __restrict__ ed,
    const int* __restrict__ offs, const int* __restrict__ csr,
    const float* __restrict__ bias, const float* __restrict__ gamma,
    const float* __restrict__ beta, const float* __restrict__ resid,
    float* __restrict__ out_f32, uint4* __restrict__ out_bf,
    const float* __restrict__ uns, const float* __restrict__ und,
    float* __restrict__ es_next, float* __restrict__ ed_next, int Nn) {
  constexpr int CHK = 8;
  int tid = threadIdx.x;
  int l = tid & 63;
  int q = l & 15;
  int n = blockIdx.x * 16 + (tid >> 6) * 4 + (l >> 4);
  if (n >= Nn) return;
  int hh = q >> 2;
  unsigned c0 = q * 8;
  float edn = ed[n * 4 + hh];
  float e0 = es[n * 4 + hh] + edn;   // self loop; softmax shift-invariant
  e0 = e0 > 0.f ? e0 : 0.2f * e0;
  float w0 = __expf(e0);
  float den = w0;
  float acc[8];
  {
    uint4 u = hbf[(unsigned)n * 16 + q];
    acc[0] = w0 * bf_lo(u.x); acc[1] = w0 * bf_hi(u.x);
    acc[2] = w0 * bf_lo(u.y); acc[3] = w0 * bf_hi(u.y);
    acc[4] = w0 * bf_lo(u.z); acc[5] = w0 * bf_hi(u.z);
    acc[6] = w0 * bf_lo(u.w); acc[7] = w0 * bf_hi(u.w);
  }
  int beg = offs[n], end = offs[n + 1];
  for (int base = beg; base < end; base += CHK) {
    int cnt = end - base;   // >=1
    int s[CHK];
#pragma unroll
    for (int j = 0; j < CHK; ++j) s[j] = (j < cnt) ? csr[base + j] : n;
    uint4 hv[CHK];
#pragma unroll
    for (int j = 0; j < CHK; ++j) hv[j] = hbf[(unsigned)s[j] * 16 + q];
    float w[CHK];
#pragma unroll
    for (int j = 0; j < CHK; ++j) {
      float e = es[s[j] * 4 + hh] + edn;
      e = e > 0.f ? e : 0.2f * e;
      w[j] = (j < cnt) ? __expf(e) : 0.f;
    }
#pragma unroll
    for (int j = 0; j < CHK; ++j) {
      den += w[j];
      acc[0] += w[j] * bf_lo(hv[j].x); acc[1] += w[j] * bf_hi(hv[j].x);
      acc[2] += w[j] * bf_lo(hv[j].y); acc[3] += w[j] * bf_hi(hv[j].y);
      acc[4] += w[j] * bf_lo(hv[j].z); acc[5] += w[j] * bf_hi(hv[j].z);
      acc[6] += w[j] * bf_lo(hv[j].w); acc[7] += w[j] * bf_hi(hv[j].w);
    }
  }
  float inv = 1.0f / (den + 1e-16f);
  f32x4 bi0 = *(const f32x4*)&bias[c0],  bi1 = *(const f32x4*)&bias[c0 + 4];
  f32x4 ga0 = *(const f32x4*)&gamma[c0], ga1 = *(const f32x4*)&gamma[c0 + 4];
  f32x4 be0 = *(const f32x4*)&beta[c0],  be1 = *(const f32x4*)&beta[c0 + 4];
  f32x4 r0 = (f32x4){0.f,0.f,0.f,0.f}, r1 = r0;
  if (RES) {
    r0 = *(const f32x4*)&resid[(size_t)n * 128 + c0];
    r1 = *(const f32x4*)&resid[(size_t)n * 128 + c0 + 4];
  }
  float o[8];
#pragma unroll
  for (int k = 0; k < 8; ++k) {
    float bi = k < 4 ? bi0[k] : bi1[k - 4];
    float ga = k < 4 ? ga0[k] : ga1[k - 4];
    float be = k < 4 ? be0[k] : be1[k - 4];
    float rv = k < 4 ? r0[k] : r1[k - 4];
    float v = acc[k] * inv + bi;
    if (RES) v += rv;
    v = ga * v * BN_INV + be;
    o[k] = v > 0.f ? v : __expf(v) - 1.f;
  }
  if (WRITE_F32) {
    f32x4 f0 = {o[0], o[1], o[2], o[3]}, f1 = {o[4], o[5], o[6], o[7]};
    *(f32x4*)&out_f32[(size_t)n * 128 + c0] = f0;
    *(f32x4*)&out_f32[(size_t)n * 128 + c0 + 4] = f1;
  }
  uint4 p;
  p.x = bf16rne(o[0]) | (bf16rne(o[1]) << 16);
  p.y = bf16rne(o[2]) | (bf16rne(o[3]) << 16);
  p.z = bf16rne(o[4]) | (bf16rne(o[5]) << 16);
  p.w = bf16rne(o[6]) | (bf16rne(o[7]) << 16);
  out_bf[(unsigned)n * 16 + q] = p;
  // next-layer attention coefficients: es_next = act . u  (16-lane reduce)
  if (NEXT_NH == 4) {
    const f32x4* uns4 = (const f32x4*)uns;
    const f32x4* und4 = (const f32x4*)und;
    f32x4 ps = (f32x4){0.f,0.f,0.f,0.f}, pd = ps;
#pragma unroll
    for (int k = 0; k < 8; ++k) {
      f32x4 us = uns4[c0 + k], ud = und4[c0 + k];
#pragma unroll
      for (int h = 0; h < 4; ++h) { ps[h] += o[k] * us[h]; pd[h] += o[k] * ud[h]; }
    }
#pragma unroll
    for (int h = 0; h < 4; ++h)
#pragma unroll
      for (int m = 1; m < 16; m <<= 1) {
        ps[h] += __shfl_xor(ps[h], m);
        pd[h] += __shfl_xor(pd[h], m);
      }
    if (q == 0) {
#pragma unroll
      for (int h = 0; h < 4; ++h) {
        es_next[n * 4 + h] = ps[h];
        ed_next[n * 4 + h] = pd[h];
      }
    }
  } else {
    float ps = 0.f, pd = 0.f;
#pragma unroll
    for (int k = 0; k < 8; ++k) { ps += o[k] * uns[c0 + k]; pd += o[k] * und[c0 + k]; }
#pragma unroll
    for (int m = 1; m < 16; m <<= 1) { ps += __shfl_xor(ps, m); pd += __shfl_xor(pd, m); }
    if (q == 0) { es_next[n] = ps; ed_next[n] = pd; }
  }
}

// --- layer-2 aggregation (H=1, O=32): 16 lanes/node (2 ch/lane), 4 nodes/wave ---

__global__ __launch_bounds__(256) void gat_agg32(const unsigned* __restrict__ hb,
    const float* __restrict__ es, const float* __restrict__ ed,
    const int* __restrict__ offs, const int* __restrict__ csr,
    const float* __restrict__ bias, float* __restrict__ h2, int Nn) {
  constexpr int CHK = 8;
  int tid = threadIdx.x;
  int l = tid & 63;
  int q = l & 15;
  int n = blockIdx.x * 16 + (tid >> 6) * 4 + (l >> 4);
  if (n >= Nn) return;
  float edn = ed[n];
  float e0 = es[n] + edn;
  e0 = e0 > 0.f ? e0 : 0.2f * e0;
  float w0 = __expf(e0);
  float den = w0;
  unsigned uself = hb[(unsigned)n * 16 + q];
  float accx = w0 * bf_lo(uself), accy = w0 * bf_hi(uself);
  int beg = offs[n], end = offs[n + 1];
  for (int base = beg; base < end; base += CHK) {
    int cnt = end - base;
    int s[CHK];
#pragma unroll
    for (int j = 0; j < CHK; ++j) s[j] = (j < cnt) ? csr[base + j] : n;
    unsigned u[CHK];
#pragma unroll
    for (int j = 0; j < CHK; ++j) u[j] = hb[(unsigned)s[j] * 16 + q];
    float w[CHK];
#pragma unroll
    for (int j = 0; j < CHK; ++j) {
      float e = es[s[j]] + edn;
      e = e > 0.f ? e : 0.2f * e;
      w[j] = (j < cnt) ? __expf(e) : 0.f;
    }
#pragma unroll
    for (int j = 0; j < CHK; ++j) {
      den += w[j];
      accx += w[j] * bf_lo(u[j]);
      accy += w[j] * bf_hi(u[j]);
    }
  }
  float inv = 1.0f / (den + 1e-16f);
  float2 bi = *(const float2*)&bias[2 * q];
  float2 o;
  o.x = accx * inv + bi.x;
  o.y = accy * inv + bi.y;
  *(float2*)&h2[(size_t)n * 32 + 2 * q] = o;
}

// -------- head: mean-pool (sorted-batch range), conv1d x2, MLP, log_softmax ------

__global__ __launch_bounds__(256) void head_kernel(const float* __restrict__ h2,
    const int* __restrict__ batch,
    const float* __restrict__ c0w, const float* __restrict__ c0b,
    const float* __restrict__ cg0, const float* __restrict__ cb0,
    const float* __restrict__ c1w, const float* __restrict__ c1b,
    const float* __restrict__ l1w, const float* __restrict__ l1b,
    const float* __restrict__ l2w, const float* __restrict__ l2b,
    float* __restrict__ out) {
  int b = blockIdx.x;
  int t = threadIdx.x;
  __shared__ float sums[8][32];
  __shared__ float pooled[32];
  __shared__ float z1[32][32];
  __shared__ float z2[16][32];
  __shared__ float emb[16];
  __shared__ float hfc[8];
  __shared__ float logits[10];

  int lo = 0, hi = NNODES;
  while (lo < hi) { int mid = (lo + hi) >> 1; if (batch[mid] < b) lo = mid + 1; else hi = mid; }
  int start = lo;
  lo = 0; hi = NNODES;
  while (lo < hi) { int mid = (lo + hi) >> 1; if (batch[mid] < b + 1) lo = mid + 1; else hi = mid; }
  int end = lo;

  {
    int ch = t & 31, g = t >> 5;
    float s = 0.f;
    for (int i = start + g; i < end; i += 8) s += h2[(size_t)i * 32 + ch];
    sums[g][ch] = s;
  }
  __syncthreads();
  if (t < 32) {
    float s = 0.f;
#pragma unroll
    for (int g = 0; g < 8; ++g) s += sums[g][t];
    float cn = fmaxf((float)(end - start), 1.0f);
    pooled[t] = s / cn;
  }
  __syncthreads();
  for (int i = t; i < 1024; i += 256) {
    int oc = i >> 5, tt = i & 31;
    float a = c0b[oc];
#pragma unroll
    for (int k = 0; k < 5; ++k) {
      int p = tt + k - 2;
      if (p >= 0 && p < 32) a += pooled[p] * c0w[oc * 5 + k];
    }
    a = cg0[oc] * a * BN_INV + cb0[oc];
    z1[oc][tt] = a > 0.f ? a : __expf(a) - 1.f;
  }
  __syncthreads();
  for (int i = t; i < 512; i += 256) {
    int oc = i >> 5, tt = i & 31;
    float a = c1b[oc];
    for (int ic = 0; ic < 32; ++ic) {
      const float* wrow = &c1w[(oc * 32 + ic) * 5];
#pragma unroll
      for (int k = 0; k < 5; ++k) {
        int p = tt + k - 2;
        if (p >= 0 && p < 32) a += z1[ic][p] * wrow[k];
      }
    }
    z2[oc][tt] = a;
  }
  __syncthreads();
  if (t < 16) {
    float s = 0.f;
    for (int i = 0; i < 32; ++i) s += z2[t][i];
    s *= (1.0f / 32.0f);
    emb[t] = s;
    out[640 + b * 16 + t] = s;     // output 1: embed (64 x 16)
  }
  __syncthreads();
  if (t < 8) {
    float a = l1b[t];
    for (int i = 0; i < 16; ++i) a += emb[i] * l1w[i * 8 + t];
    hfc[t] = a > 0.f ? a : __expf(a) - 1.f;
  }
  __syncthreads();
  if (t < 10) {
    float a = l2b[t];
    for (int j = 0; j < 8; ++j) a += hfc[j] * l2w[j * 10 + t];
    logits[t] = a;
  }
  __syncthreads();
  if (t == 0) {
    float m = logits[0];
    for (int k = 1; k < 10; ++k) m = fmaxf(m, logits[k]);
    float s = 0.f;
    for (int k = 0; k < 10; ++k) s += __expf(logits[k] - m);
    float lse = m + logf(s);
    for (int k = 0; k < 10; ++k) out[b * 10 + k] = logits[k] - lse;  // output 0
  }
}

// ---------------- launch ----------------

extern "C" void kernel_launch(void* const* d_in, const int* in_sizes, int n_in,
                              void* d_out, int out_size, void* d_ws, size_t ws_size,
                              hipStream_t stream) {
  const float* x   = (const float*)d_in[0];
  const int* eidx  = (const int*)d_in[1];
  const int* esrc  = eidx;
  const int* edst  = eidx + NEDGES;
  const int* batch = (const int*)d_in[2];
  const float* W0  = (const float*)d_in[3];
  const float* a0s = (const float*)d_in[4];
  const float* a0d = (const float*)d_in[5];
  const float* b0  = (const float*)d_in[6];
  const float* W1  = (const float*)d_in[7];
  const float* a1s = (const float*)d_in[8];
  const float* a1d = (const float*)d_in[9];
  const float* b1  = (const float*)d_in[10];
  const float* W2  = (const float*)d_in[11];
  const float* a2s = (const float*)d_in[12];
  const float* a2d = (const float*)d_in[13];
  const float* b2  = (const float*)d_in[14];
  const float* g0  = (const float*)d_in[15];
  const float* be0 = (const float*)d_in[16];
  const float* g1  = (const float*)d_in[17];
  const float* be1 = (const float*)d_in[18];
  const float* c0w = (const float*)d_in[19];
  const float* c0b = (const float*)d_in[20];
  const float* cg0 = (const float*)d_in[21];
  const float* cb0 = (const float*)d_in[22];
  const float* c1w = (const float*)d_in[23];
  const float* c1b = (const float*)d_in[24];
  const float* l1w = (const float*)d_in[25];
  const float* l1b = (const float*)d_in[26];
  const float* l2w = (const float*)d_in[27];
  const float* l2b = (const float*)d_in[28];

  char* ws = (char*)d_ws;
  int*            deg    = (int*)(ws + 0);
  int*            cursor = (int*)(ws + 208448);
  int*            offs   = (int*)(ws + 408448);
  float*          esA    = (float*)(ws + 608512);
  float*          edA    = (float*)(ws + 1408512);
  float*          esB    = (float*)(ws + 2208512);
  float*          edB    = (float*)(ws + 3008512);
  int*            csr    = (int*)(ws + 3808512);
  unsigned*       Abf    = (unsigned*)(ws + 7008512);    // N x 64 uints (bf16 pairs)
  unsigned*       hbf    = (unsigned*)(ws + 19808512);   // N x 64 uints
  float*          act0   = (float*)(ws + 32608512);      // N x 128 f32 (h2 reuse)
  unsigned short* W0t    = (unsigned short*)(ws + 58208512);
  unsigned short* W1t    = (unsigned short*)(ws + 58241280);
  unsigned short* W2t    = (unsigned short*)(ws + 58274048);
  float*          u0s    = (float*)(ws + 58282240);
  float*          u0d    = (float*)(ws + 58284288);
  float*          u1s    = (float*)(ws + 58286336);
  float*          u1d    = (float*)(ws + 58288384);
  float*          u2s    = (float*)(ws + 58290432);
  float*          u2d    = (float*)(ws + 58290944);
  float*          h2     = act0;
  float*          out    = (float*)d_out;

  hipMemsetAsync(d_ws, 0, 200000, stream);   // deg = 0

  count_deg<<<(NEDGES + 255) / 256, 256, 0, stream>>>(edst, deg, NEDGES);
  scan_kernel<<<1, 1024, 0, stream>>>(deg, offs, cursor, NNODES);
  fill_csr<<<(NEDGES + 255) / 256, 256, 0, stream>>>(esrc, edst, cursor, csr, NEDGES);

  prep_kernel<<<147, 256, 0, stream>>>(W0, W1, W2, a0s, a0d, a1s, a1d, a2s, a2d,
                                       W0t, W1t, W2t, u0s, u0d, u1s, u1d, u2s, u2d);
  xprep_kernel<<<NNODES / 4, 256, 0, stream>>>(x, Abf, u0s, u0d, esA, edA, NNODES);

  const int ggrid = (NNODES + 63) / 64;
  const int agrid = (NNODES + 15) / 16;

  // --- layer 0 ---
  gemm_mfma<128><<<ggrid, 256, 0, stream>>>((const unsigned short*)Abf, W0t,
                                            (unsigned short*)hbf, NNODES);
  gat_agg128<false, true, 4><<<agrid, 256, 0, stream>>>(
      (const uint4*)hbf, esA, edA, offs, csr, b0, g0, be0, nullptr,
      act0, (uint4*)Abf, u1s, u1d, esB, edB, NNODES);

  // --- layer 1 (residual) ---
  gemm_mfma<128><<<ggrid, 256, 0, stream>>>((const unsigned short*)Abf, W1t,
                                            (unsigned short*)hbf, NNODES);
  gat_agg128<true, false, 1><<<agrid, 256, 0, stream>>>(
      (const uint4*)hbf, esB, edB, offs, csr, b1, g1, be1, act0,
      nullptr, (uint4*)Abf, u2s, u2d, esA, edA, NNODES);

  // --- layer 2 (H=1, O=32) ---
  gemm_mfma<32><<<ggrid, 256, 0, stream>>>((const unsigned short*)Abf, W2t,
                                           (unsigned short*)hbf, NNODES);
  gat_agg32<<<agrid, 256, 0, stream>>>(hbf, esA, edA, offs, csr, b2, h2, NNODES);

  // --- head (pool fused) ---
  head_kernel<<<64, 256, 0, stream>>>(h2, batch, c0w, c0b, cg0, cb0,
                                      c1w, c1b, l1w, l1b, l2w, l2b, out);
}

// Round 9
// 340.958 us; speedup vs baseline: 1.6747x; 1.1795x over previous
//
#include <hip/hip_runtime.h>
#include <hip/hip_bf16.h>

// GATModel: 3-layer GAT (heads 4/4/1) + BN/ELU + residual + mean-pool + conv1d head.
// N=50000 nodes, E=800000 edges (+N self-loops handled analytically).
//
// R8 changes vs R7 (scan_kernel was 70us = 17%: single-block serial carry-loop
// scan, occupancy 0.17%):
//  - hierarchical scan: scan_local (49 blocks, wave shfl + LDS wave-offsets,
//    block-local exclusive prefix + block totals) + scan_finish (wave-0 scans
//    49 totals in-register, add base, emit offs/cursor). ~8us total.
//
// Workspace (~58.5 MB): see offsets in kernel_launch.

#define NNODES 50000
#define NEDGES 800000
#define BN_INV 0.9999950000374997f  // 1/sqrt(1+1e-5)
#define SCAN_NB 49                  // ceil(NNODES/1024)

typedef __attribute__((ext_vector_type(8))) short bf16x8;
typedef __attribute__((ext_vector_type(4))) float f32x4;

__device__ __forceinline__ unsigned bf16rne(float f) {   // fp32 -> bf16 bits (RNE)
  unsigned u = __float_as_uint(f);
  return (u + 0x7fffu + ((u >> 16) & 1u)) >> 16;
}
__device__ __forceinline__ float bf_lo(unsigned u) { return __uint_as_float(u << 16); }
__device__ __forceinline__ float bf_hi(unsigned u) { return __uint_as_float(u & 0xffff0000u); }
__device__ __forceinline__ float bf_us(unsigned short s) { return __uint_as_float(((unsigned)s) << 16); }

// ---------------- CSR build ----------------

__global__ __launch_bounds__(256) void count_deg(const int* __restrict__ dst,
                                                 int* __restrict__ deg, int E) {
  int i = blockIdx.x * 256 + threadIdx.x;
  if (i < E) atomicAdd(&deg[dst[i]], 1);
}

// block-local exclusive scan: loc[i] = prefix within block, bsum[b] = block total
__global__ __launch_bounds__(1024) void scan_local(const int* __restrict__ deg,
    int* __restrict__ loc, int* __restrict__ bsum, int Nn) {
  __shared__ int wsum[16];
  __shared__ int woff[17];
  int b = blockIdx.x, t = threadIdx.x, lane = t & 63, w = t >> 6;
  int i = b * 1024 + t;
  int v = (i < Nn) ? deg[i] : 0;
  int incl = v;
#pragma unroll
  for (int o = 1; o < 64; o <<= 1) { int x = __shfl_up(incl, o); if (lane >= o) incl += x; }
  if (lane == 63) wsum[w] = incl;
  __syncthreads();
  if (t == 0) {
    int r = 0;
#pragma unroll
    for (int j = 0; j < 16; ++j) { woff[j] = r; r += wsum[j]; }
    bsum[b] = r;
  }
  __syncthreads();
  if (i < Nn) loc[i] = woff[w] + incl - v;
}

// add scanned block bases; emit offs + cursor; offs[Nn] = total
__global__ __launch_bounds__(1024) void scan_finish(const int* __restrict__ loc,
    const int* __restrict__ bsum, int* __restrict__ offs, int* __restrict__ cursor,
    int Nn, int nb) {
  __shared__ int boff[65];
  int b = blockIdx.x, t = threadIdx.x;
  if (t < 64) {
    int v = (t < nb) ? bsum[t] : 0;
    int incl = v;
#pragma unroll
    for (int o = 1; o < 64; o <<= 1) { int x = __shfl_up(incl, o); if (t >= o) incl += x; }
    boff[t + 1] = incl;
    if (t == 0) boff[0] = 0;
  }
  __syncthreads();
  int base = boff[b];
  int i = b * 1024 + t;
  if (i < Nn) { int o = loc[i] + base; offs[i] = o; cursor[i] = o; }
  if (b == 0 && t == 0) offs[Nn] = boff[nb];
}

__global__ __launch_bounds__(256) void fill_csr(const int* __restrict__ src,
    const int* __restrict__ dst, int* __restrict__ cursor,
    int* __restrict__ csr, int E) {
  int i = blockIdx.x * 256 + threadIdx.x;
  if (i < E) {
    int d = dst[i];
    int pos = atomicAdd(&cursor[d], 1);
    csr[pos] = src[i];
  }
}

// --------- prep: W0t/W1t/W2t (bf16, transposed) + u = W @ a_{s,d} vectors --------

__global__ __launch_bounds__(256) void prep_kernel(
    const float* __restrict__ W0, const float* __restrict__ W1, const float* __restrict__ W2,
    const float* __restrict__ a0s, const float* __restrict__ a0d,
    const float* __restrict__ a1s, const float* __restrict__ a1d,
    const float* __restrict__ a2s, const float* __restrict__ a2d,
    unsigned short* __restrict__ W0t, unsigned short* __restrict__ W1t,
    unsigned short* __restrict__ W2t,
    float* __restrict__ u0s, float* __restrict__ u0d,
    float* __restrict__ u1s, float* __restrict__ u1d,
    float* __restrict__ u2s, float* __restrict__ u2d) {
  int b = blockIdx.x, t = threadIdx.x;
  if (b < 64) {                       // W0t
    int idx = b * 256 + t; int c = idx >> 7, k = idx & 127;
    W0t[idx] = (unsigned short)bf16rne(W0[k * 128 + c]);
  } else if (b < 128) {               // W1t
    int idx = (b - 64) * 256 + t; int c = idx >> 7, k = idx & 127;
    W1t[idx] = (unsigned short)bf16rne(W1[k * 128 + c]);
  } else if (b < 144) {               // W2t (32 x 128)
    int idx = (b - 128) * 256 + t; int c = idx >> 7, k = idx & 127;
    W2t[idx] = (unsigned short)bf16rne(W2[k * 32 + c]);
  } else if (b == 144) {              // u0
    for (int it = 0; it < 4; ++it) {
      int idx = it * 256 + t;         // 0..1023
      int k = idx >> 3, rem = idx & 7, h = rem >> 1, sd = rem & 1;
      const float* av = sd ? a0d : a0s;
      float s = 0.f;
      for (int o = 0; o < 32; ++o) s += W0[k * 128 + h * 32 + o] * av[h * 32 + o];
      (sd ? u0d : u0s)[k * 4 + h] = s;
    }
  } else if (b == 145) {              // u1
    for (int it = 0; it < 4; ++it) {
      int idx = it * 256 + t;
      int k = idx >> 3, rem = idx & 7, h = rem >> 1, sd = rem & 1;
      const float* av = sd ? a1d : a1s;
      float s = 0.f;
      for (int o = 0; o < 32; ++o) s += W1[k * 128 + h * 32 + o] * av[h * 32 + o];
      (sd ? u1d : u1s)[k * 4 + h] = s;
    }
  } else {                            // u2 (256 outputs)
    int k = t >> 1, sd = t & 1;
    const float* av = sd ? a2d : a2s;
    float s = 0.f;
    for (int o = 0; o < 32; ++o) s += W2[k * 32 + o] * av[o];
    (sd ? u2d : u2s)[k] = s;
  }
}

// --------- xprep: x(f32) -> xbf(bf16) + es0/ed0 = x . u0 (one wave per node) -----

__global__ __launch_bounds__(256) void xprep_kernel(const float* __restrict__ x,
    unsigned* __restrict__ xbf, const float* __restrict__ u0s,
    const float* __restrict__ u0d, float* __restrict__ es, float* __restrict__ ed,
    int Nn) {
  int n = blockIdx.x * 4 + (threadIdx.x >> 6);
  if (n >= Nn) return;
  int l = threadIdx.x & 63;
  int c0 = 2 * l;
  float2 v = *(const float2*)&x[(size_t)n * 128 + c0];
  xbf[(size_t)n * 64 + l] = bf16rne(v.x) | (bf16rne(v.y) << 16);
  float ps[4], pd[4];
#pragma unroll
  for (int h = 0; h < 4; ++h) {
    ps[h] = v.x * u0s[c0 * 4 + h] + v.y * u0s[(c0 + 1) * 4 + h];
    pd[h] = v.x * u0d[c0 * 4 + h] + v.y * u0d[(c0 + 1) * 4 + h];
  }
#pragma unroll
  for (int h = 0; h < 4; ++h)
#pragma unroll
    for (int o = 32; o; o >>= 1) { ps[h] += __shfl_xor(ps[h], o); pd[h] += __shfl_xor(pd[h], o); }
  if (l == 0) {
#pragma unroll
    for (int h = 0; h < 4; ++h) { es[n * 4 + h] = ps[h]; ed[n * 4 + h] = pd[h]; }
  }
}

// --------- MFMA GEMM: H(N x NC, bf16) = A(N x 128, bf16) @ W(128 x NC, bf16) -----

template <int NC>
__global__ __launch_bounds__(256) void gemm_mfma(const unsigned short* __restrict__ Abf,
    const unsigned short* __restrict__ Wt, unsigned short* __restrict__ Hbf,
    int Nrows) {
  constexpr int NT = NC / 16;
  __shared__ unsigned short lw[NC][136];
  int tid = threadIdx.x;
  for (int idx = tid; idx < NC * 16; idx += 256) {
    int c = idx >> 4, k0 = (idx & 15) * 8;
    *(uint4*)&lw[c][k0] = *(const uint4*)&Wt[c * 128 + k0];
  }
  __syncthreads();
  int w = tid >> 6, l = tid & 63;
  int g = l >> 4, i = l & 15;
  int rbase = blockIdx.x * 64 + w * 16;
  int arow = rbase + i; arow = arow < Nrows ? arow : Nrows - 1;
  bf16x8 a[4];
#pragma unroll
  for (int kk = 0; kk < 4; ++kk)
    a[kk] = *(const bf16x8*)&Abf[(size_t)arow * 128 + kk * 32 + g * 8];
  f32x4 acc[NT];
#pragma unroll
  for (int t = 0; t < NT; ++t) acc[t] = (f32x4){0.f, 0.f, 0.f, 0.f};
#pragma unroll
  for (int kk = 0; kk < 4; ++kk) {
#pragma unroll
    for (int t = 0; t < NT; ++t) {
      bf16x8 b = *(const bf16x8*)&lw[t * 16 + i][kk * 32 + g * 8];
      acc[t] = __builtin_amdgcn_mfma_f32_16x16x32_bf16(a[kk], b, acc[t], 0, 0, 0);
    }
  }
  int crow0 = rbase + g * 4;
#pragma unroll
  for (int t = 0; t < NT; ++t)
#pragma unroll
    for (int r = 0; r < 4; ++r) {
      int row = crow0 + r;
      if (row < Nrows)
        Hbf[(size_t)row * NC + t * 16 + i] = (unsigned short)bf16rne(acc[t][r]);
    }
}

// --- GAT aggregation (HH=128, 4 heads): 16 lanes/node, 4 nodes/wave, bf16 h ---

template <bool RES, bool WRITE_F32, int NEXT_NH>
__global__ __launch_bounds__(256) void gat_agg128(const uint4* __restrict__ hbf,
    const float* __restrict__ es, const float* __restrict__ ed,
    const int* __restrict__ offs, const int* __restrict__ csr,
    const float* __restrict__ bias, const float* __restrict__ gamma,
    const float* __restrict__ beta, const float* __restrict__ resid,
    float* __restrict__ out_f32, uint4* __restrict__ out_bf,
    const float* __restrict__ uns, const float* __restrict__ und,
    float* __restrict__ es_next, float* __restrict__ ed_next, int Nn) {
  constexpr int CHK = 8;
  int tid = threadIdx.x;
  int l = tid & 63;
  int q = l & 15;
  int n = blockIdx.x * 16 + (tid >> 6) * 4 + (l >> 4);
  if (n >= Nn) return;
  int hh = q >> 2;
  unsigned c0 = q * 8;
  float edn = ed[n * 4 + hh];
  float e0 = es[n * 4 + hh] + edn;   // self loop; softmax shift-invariant
  e0 = e0 > 0.f ? e0 : 0.2f * e0;
  float w0 = __expf(e0);
  float den = w0;
  float acc[8];
  {
    uint4 u = hbf[(unsigned)n * 16 + q];
    acc[0] = w0 * bf_lo(u.x); acc[1] = w0 * bf_hi(u.x);
    acc[2] = w0 * bf_lo(u.y); acc[3] = w0 * bf_hi(u.y);
    acc[4] = w0 * bf_lo(u.z); acc[5] = w0 * bf_hi(u.z);
    acc[6] = w0 * bf_lo(u.w); acc[7] = w0 * bf_hi(u.w);
  }
  int beg = offs[n], end = offs[n + 1];
  for (int base = beg; base < end; base += CHK) {
    int cnt = end - base;   // >=1
    int s[CHK];
#pragma unroll
    for (int j = 0; j < CHK; ++j) s[j] = (j < cnt) ? csr[base + j] : n;
    uint4 hv[CHK];
#pragma unroll
    for (int j = 0; j < CHK; ++j) hv[j] = hbf[(unsigned)s[j] * 16 + q];
    float w[CHK];
#pragma unroll
    for (int j = 0; j < CHK; ++j) {
      float e = es[s[j] * 4 + hh] + edn;
      e = e > 0.f ? e : 0.2f * e;
      w[j] = (j < cnt) ? __expf(e) : 0.f;
    }
#pragma unroll
    for (int j = 0; j < CHK; ++j) {
      den += w[j];
      acc[0] += w[j] * bf_lo(hv[j].x); acc[1] += w[j] * bf_hi(hv[j].x);
      acc[2] += w[j] * bf_lo(hv[j].y); acc[3] += w[j] * bf_hi(hv[j].y);
      acc[4] += w[j] * bf_lo(hv[j].z); acc[5] += w[j] * bf_hi(hv[j].z);
      acc[6] += w[j] * bf_lo(hv[j].w); acc[7] += w[j] * bf_hi(hv[j].w);
    }
  }
  float inv = 1.0f / (den + 1e-16f);
  f32x4 bi0 = *(const f32x4*)&bias[c0],  bi1 = *(const f32x4*)&bias[c0 + 4];
  f32x4 ga0 = *(const f32x4*)&gamma[c0], ga1 = *(const f32x4*)&gamma[c0 + 4];
  f32x4 be0 = *(const f32x4*)&beta[c0],  be1 = *(const f32x4*)&beta[c0 + 4];
  f32x4 r0 = (f32x4){0.f,0.f,0.f,0.f}, r1 = r0;
  if (RES) {
    r0 = *(const f32x4*)&resid[(size_t)n * 128 + c0];
    r1 = *(const f32x4*)&resid[(size_t)n * 128 + c0 + 4];
  }
  float o[8];
#pragma unroll
  for (int k = 0; k < 8; ++k) {
    float bi = k < 4 ? bi0[k] : bi1[k - 4];
    float ga = k < 4 ? ga0[k] : ga1[k - 4];
    float be = k < 4 ? be0[k] : be1[k - 4];
    float rv = k < 4 ? r0[k] : r1[k - 4];
    float v = acc[k] * inv + bi;
    if (RES) v += rv;
    v = ga * v * BN_INV + be;
    o[k] = v > 0.f ? v : __expf(v) - 1.f;
  }
  if (WRITE_F32) {
    f32x4 f0 = {o[0], o[1], o[2], o[3]}, f1 = {o[4], o[5], o[6], o[7]};
    *(f32x4*)&out_f32[(size_t)n * 128 + c0] = f0;
    *(f32x4*)&out_f32[(size_t)n * 128 + c0 + 4] = f1;
  }
  uint4 p;
  p.x = bf16rne(o[0]) | (bf16rne(o[1]) << 16);
  p.y = bf16rne(o[2]) | (bf16rne(o[3]) << 16);
  p.z = bf16rne(o[4]) | (bf16rne(o[5]) << 16);
  p.w = bf16rne(o[6]) | (bf16rne(o[7]) << 16);
  out_bf[(unsigned)n * 16 + q] = p;
  // next-layer attention coefficients: es_next = act . u  (16-lane reduce)
  if (NEXT_NH == 4) {
    const f32x4* uns4 = (const f32x4*)uns;
    const f32x4* und4 = (const f32x4*)und;
    f32x4 ps = (f32x4){0.f,0.f,0.f,0.f}, pd = ps;
#pragma unroll
    for (int k = 0; k < 8; ++k) {
      f32x4 us = uns4[c0 + k], ud = und4[c0 + k];
#pragma unroll
      for (int h = 0; h < 4; ++h) { ps[h] += o[k] * us[h]; pd[h] += o[k] * ud[h]; }
    }
#pragma unroll
    for (int h = 0; h < 4; ++h)
#pragma unroll
      for (int m = 1; m < 16; m <<= 1) {
        ps[h] += __shfl_xor(ps[h], m);
        pd[h] += __shfl_xor(pd[h], m);
      }
    if (q == 0) {
#pragma unroll
      for (int h = 0; h < 4; ++h) {
        es_next[n * 4 + h] = ps[h];
        ed_next[n * 4 + h] = pd[h];
      }
    }
  } else {
    float ps = 0.f, pd = 0.f;
#pragma unroll
    for (int k = 0; k < 8; ++k) { ps += o[k] * uns[c0 + k]; pd += o[k] * und[c0 + k]; }
#pragma unroll
    for (int m = 1; m < 16; m <<= 1) { ps += __shfl_xor(ps, m); pd += __shfl_xor(pd, m); }
    if (q == 0) { es_next[n] = ps; ed_next[n] = pd; }
  }
}

// --- layer-2 aggregation (H=1, O=32): 16 lanes/node (2 ch/lane), 4 nodes/wave ---

__global__ __launch_bounds__(256) void gat_agg32(const unsigned* __restrict__ hb,
    const float* __restrict__ es, const float* __restrict__ ed,
    const int* __restrict__ offs, const int* __restrict__ csr,
    const float* __restrict__ bias, float* __restrict__ h2, int Nn) {
  constexpr int CHK = 8;
  int tid = threadIdx.x;
  int l = tid & 63;
  int q = l & 15;
  int n = blockIdx.x * 16 + (tid >> 6) * 4 + (l >> 4);
  if (n >= Nn) return;
  float edn = ed[n];
  float e0 = es[n] + edn;
  e0 = e0 > 0.f ? e0 : 0.2f * e0;
  float w0 = __expf(e0);
  float den = w0;
  unsigned uself = hb[(unsigned)n * 16 + q];
  float accx = w0 * bf_lo(uself), accy = w0 * bf_hi(uself);
  int beg = offs[n], end = offs[n + 1];
  for (int base = beg; base < end; base += CHK) {
    int cnt = end - base;
    int s[CHK];
#pragma unroll
    for (int j = 0; j < CHK; ++j) s[j] = (j < cnt) ? csr[base + j] : n;
    unsigned u[CHK];
#pragma unroll
    for (int j = 0; j < CHK; ++j) u[j] = hb[(unsigned)s[j] * 16 + q];
    float w[CHK];
#pragma unroll
    for (int j = 0; j < CHK; ++j) {
      float e = es[s[j]] + edn;
      e = e > 0.f ? e : 0.2f * e;
      w[j] = (j < cnt) ? __expf(e) : 0.f;
    }
#pragma unroll
    for (int j = 0; j < CHK; ++j) {
      den += w[j];
      accx += w[j] * bf_lo(u[j]);
      accy += w[j] * bf_hi(u[j]);
    }
  }
  float inv = 1.0f / (den + 1e-16f);
  float2 bi = *(const float2*)&bias[2 * q];
  float2 o;
  o.x = accx * inv + bi.x;
  o.y = accy * inv + bi.y;
  *(float2*)&h2[(size_t)n * 32 + 2 * q] = o;
}

// -------- head: mean-pool (sorted-batch range), conv1d x2, MLP, log_softmax ------

__global__ __launch_bounds__(256) void head_kernel(const float* __restrict__ h2,
    const int* __restrict__ batch,
    const float* __restrict__ c0w, const float* __restrict__ c0b,
    const float* __restrict__ cg0, const float* __restrict__ cb0,
    const float* __restrict__ c1w, const float* __restrict__ c1b,
    const float* __restrict__ l1w, const float* __restrict__ l1b,
    const float* __restrict__ l2w, const float* __restrict__ l2b,
    float* __restrict__ out) {
  int b = blockIdx.x;
  int t = threadIdx.x;
  __shared__ float sums[8][32];
  __shared__ float pooled[32];
  __shared__ float z1[32][32];
  __shared__ float z2[16][32];
  __shared__ float emb[16];
  __shared__ float hfc[8];
  __shared__ float logits[10];

  int lo = 0, hi = NNODES;
  while (lo < hi) { int mid = (lo + hi) >> 1; if (batch[mid] < b) lo = mid + 1; else hi = mid; }
  int start = lo;
  lo = 0; hi = NNODES;
  while (lo < hi) { int mid = (lo + hi) >> 1; if (batch[mid] < b + 1) lo = mid + 1; else hi = mid; }
  int end = lo;

  {
    int ch = t & 31, g = t >> 5;
    float s = 0.f;
    for (int i = start + g; i < end; i += 8) s += h2[(size_t)i * 32 + ch];
    sums[g][ch] = s;
  }
  __syncthreads();
  if (t < 32) {
    float s = 0.f;
#pragma unroll
    for (int g = 0; g < 8; ++g) s += sums[g][t];
    float cn = fmaxf((float)(end - start), 1.0f);
    pooled[t] = s / cn;
  }
  __syncthreads();
  for (int i = t; i < 1024; i += 256) {
    int oc = i >> 5, tt = i & 31;
    float a = c0b[oc];
#pragma unroll
    for (int k = 0; k < 5; ++k) {
      int p = tt + k - 2;
      if (p >= 0 && p < 32) a += pooled[p] * c0w[oc * 5 + k];
    }
    a = cg0[oc] * a * BN_INV + cb0[oc];
    z1[oc][tt] = a > 0.f ? a : __expf(a) - 1.f;
  }
  __syncthreads();
  for (int i = t; i < 512; i += 256) {
    int oc = i >> 5, tt = i & 31;
    float a = c1b[oc];
    for (int ic = 0; ic < 32; ++ic) {
      const float* wrow = &c1w[(oc * 32 + ic) * 5];
#pragma unroll
      for (int k = 0; k < 5; ++k) {
        int p = tt + k - 2;
        if (p >= 0 && p < 32) a += z1[ic][p] * wrow[k];
      }
    }
    z2[oc][tt] = a;
  }
  __syncthreads();
  if (t < 16) {
    float s = 0.f;
    for (int i = 0; i < 32; ++i) s += z2[t][i];
    s *= (1.0f / 32.0f);
    emb[t] = s;
    out[640 + b * 16 + t] = s;     // output 1: embed (64 x 16)
  }
  __syncthreads();
  if (t < 8) {
    float a = l1b[t];
    for (int i = 0; i < 16; ++i) a += emb[i] * l1w[i * 8 + t];
    hfc[t] = a > 0.f ? a : __expf(a) - 1.f;
  }
  __syncthreads();
  if (t < 10) {
    float a = l2b[t];
    for (int j = 0; j < 8; ++j) a += hfc[j] * l2w[j * 10 + t];
    logits[t] = a;
  }
  __syncthreads();
  if (t == 0) {
    float m = logits[0];
    for (int k = 1; k < 10; ++k) m = fmaxf(m, logits[k]);
    float s = 0.f;
    for (int k = 0; k < 10; ++k) s += __expf(logits[k] - m);
    float lse = m + logf(s);
    for (int k = 0; k < 10; ++k) out[b * 10 + k] = logits[k] - lse;  // output 0
  }
}

// ---------------- launch ----------------

extern "C" void kernel_launch(void* const* d_in, const int* in_sizes, int n_in,
                              void* d_out, int out_size, void* d_ws, size_t ws_size,
                              hipStream_t stream) {
  const float* x   = (const float*)d_in[0];
  const int* eidx  = (const int*)d_in[1];
  const int* esrc  = eidx;
  const int* edst  = eidx + NEDGES;
  const int* batch = (const int*)d_in[2];
  const float* W0  = (const float*)d_in[3];
  const float* a0s = (const float*)d_in[4];
  const float* a0d = (const float*)d_in[5];
  const float* b0  = (const float*)d_in[6];
  const float* W1  = (const float*)d_in[7];
  const float* a1s = (const float*)d_in[8];
  const float* a1d = (const float*)d_in[9];
  const float* b1  = (const float*)d_in[10];
  const float* W2  = (const float*)d_in[11];
  const float* a2s = (const float*)d_in[12];
  const float* a2d = (const float*)d_in[13];
  const float* b2  = (const float*)d_in[14];
  const float* g0  = (const float*)d_in[15];
  const float* be0 = (const float*)d_in[16];
  const float* g1  = (const float*)d_in[17];
  const float* be1 = (const float*)d_in[18];
  const float* c0w = (const float*)d_in[19];
  const float* c0b = (const float*)d_in[20];
  const float* cg0 = (const float*)d_in[21];
  const float* cb0 = (const float*)d_in[22];
  const float* c1w = (const float*)d_in[23];
  const float* c1b = (const float*)d_in[24];
  const float* l1w = (const float*)d_in[25];
  const float* l1b = (const float*)d_in[26];
  const float* l2w = (const float*)d_in[27];
  const float* l2b = (const float*)d_in[28];

  char* ws = (char*)d_ws;
  int*            deg    = (int*)(ws + 0);
  int*            cursor = (int*)(ws + 208448);
  int*            offs   = (int*)(ws + 408448);
  float*          esA    = (float*)(ws + 608512);
  float*          edA    = (float*)(ws + 1408512);
  float*          esB    = (float*)(ws + 2208512);
  float*          edB    = (float*)(ws + 3008512);
  int*            csr    = (int*)(ws + 3808512);
  unsigned*       Abf    = (unsigned*)(ws + 7008512);    // N x 64 uints (bf16 pairs)
  unsigned*       hbf    = (unsigned*)(ws + 19808512);   // N x 64 uints
  float*          act0   = (float*)(ws + 32608512);      // N x 128 f32 (h2 reuse)
  unsigned short* W0t    = (unsigned short*)(ws + 58208512);
  unsigned short* W1t    = (unsigned short*)(ws + 58241280);
  unsigned short* W2t    = (unsigned short*)(ws + 58274048);
  float*          u0s    = (float*)(ws + 58282240);
  float*          u0d    = (float*)(ws + 58284288);
  float*          u1s    = (float*)(ws + 58286336);
  float*          u1d    = (float*)(ws + 58288384);
  float*          u2s    = (float*)(ws + 58290432);
  float*          u2d    = (float*)(ws + 58290944);
  int*            sloc   = (int*)(ws + 58291456);        // 50000 i32 scan scratch
  int*            sbsum  = (int*)(ws + 58491456);        // 49 i32 block sums
  float*          h2     = act0;
  float*          out    = (float*)d_out;

  hipMemsetAsync(d_ws, 0, 200000, stream);   // deg = 0

  count_deg<<<(NEDGES + 255) / 256, 256, 0, stream>>>(edst, deg, NEDGES);
  scan_local<<<SCAN_NB, 1024, 0, stream>>>(deg, sloc, sbsum, NNODES);
  scan_finish<<<SCAN_NB, 1024, 0, stream>>>(sloc, sbsum, offs, cursor, NNODES, SCAN_NB);
  fill_csr<<<(NEDGES + 255) / 256, 256, 0, stream>>>(esrc, edst, cursor, csr, NEDGES);

  prep_kernel<<<147, 256, 0, stream>>>(W0, W1, W2, a0s, a0d, a1s, a1d, a2s, a2d,
                                       W0t, W1t, W2t, u0s, u0d, u1s, u1d, u2s, u2d);
  xprep_kernel<<<NNODES / 4, 256, 0, stream>>>(x, Abf, u0s, u0d, esA, edA, NNODES);

  const int ggrid = (NNODES + 63) / 64;
  const int agrid = (NNODES + 15) / 16;

  // --- layer 0 ---
  gemm_mfma<128><<<ggrid, 256, 0, stream>>>((const unsigned short*)Abf, W0t,
                                            (unsigned short*)hbf, NNODES);
  gat_agg128<false, true, 4><<<agrid, 256, 0, stream>>>(
      (const uint4*)hbf, esA, edA, offs, csr, b0, g0, be0, nullptr,
      act0, (uint4*)Abf, u1s, u1d, esB, edB, NNODES);

  // --- layer 1 (residual) ---
  gemm_mfma<128><<<ggrid, 256, 0, stream>>>((const unsigned short*)Abf, W1t,
                                            (unsigned short*)hbf, NNODES);
  gat_agg128<true, false, 1><<<agrid, 256, 0, stream>>>(
      (const uint4*)hbf, esB, edB, offs, csr, b1, g1, be1, act0,
      nullptr, (uint4*)Abf, u2s, u2d, esA, edA, NNODES);

  // --- layer 2 (H=1, O=32) ---
  gemm_mfma<32><<<ggrid, 256, 0, stream>>>((const unsigned short*)Abf, W2t,
                                           (unsigned short*)hbf, NNODES);
  gat_agg32<<<agrid, 256, 0, stream>>>(hbf, esA, edA, offs, csr, b2, h2, NNODES);

  // --- head (pool fused) ---
  head_kernel<<<64, 256, 0, stream>>>(h2, batch, c0w, c0b, cg0, cb0,
                                      c1w, c1b, l1w, l1b, l2w, l2b, out);
}

// Round 10
// 332.295 us; speedup vs baseline: 1.7184x; 1.0261x over previous
//
#include <hip/hip_runtime.h>
#include <hip/hip_bf16.h>

// GATModel: 3-layer GAT (heads 4/4/1) + BN/ELU + residual + mean-pool + conv1d head.
// N=50000 nodes, E=800000 edges (+N self-loops handled analytically).
//
// R9 changes vs R8 (gat_agg128 66us x2 = 39%, gather-data-path bound: 218MB
// logical / ~100MB HBM per dispatch, h table 12.8MB >> 4MB/XCD L2):
//  - h tables stored as OCP fp8 e4m3 (hardware v_cvt_pk_fp8_f32 encode in GEMM
//    epilogue, v_cvt_pk_f32_fp8 decode in agg): gather bytes/edge 256B->128B.
//    es/ed still fp32 from pre-rounding activations; residual still fp32;
//    GEMM A-operand still bf16. Layer-2 h table 1.6MB -> single-XCD L2 resident.
//  - edge chunk 8 -> 16 (uint2 gathers halve in-flight register bytes) => 2x MLP.
//
// Workspace (~58.5 MB): see offsets in kernel_launch.

#define NNODES 50000
#define NEDGES 800000
#define BN_INV 0.9999950000374997f  // 1/sqrt(1+1e-5)
#define SCAN_NB 49                  // ceil(NNODES/1024)

typedef __attribute__((ext_vector_type(8))) short bf16x8;
typedef __attribute__((ext_vector_type(4))) float f32x4;
typedef __attribute__((ext_vector_type(2))) float f32x2;

__device__ __forceinline__ unsigned bf16rne(float f) {   // fp32 -> bf16 bits (RNE)
  unsigned u = __float_as_uint(f);
  return (u + 0x7fffu + ((u >> 16) & 1u)) >> 16;
}
__device__ __forceinline__ float bf_lo(unsigned u) { return __uint_as_float(u << 16); }
__device__ __forceinline__ float bf_hi(unsigned u) { return __uint_as_float(u & 0xffff0000u); }

__device__ __forceinline__ unsigned char fp8enc(float f) {  // fp32 -> OCP e4m3 (HW RNE/sat)
  return (unsigned char)(__builtin_amdgcn_cvt_pk_fp8_f32(f, f, 0u, false) & 0xffu);
}

// ---------------- CSR build ----------------

__global__ __launch_bounds__(256) void count_deg(const int* __restrict__ dst,
                                                 int* __restrict__ deg, int E) {
  int i = blockIdx.x * 256 + threadIdx.x;
  if (i < E) atomicAdd(&deg[dst[i]], 1);
}

// block-local exclusive scan: loc[i] = prefix within block, bsum[b] = block total
__global__ __launch_bounds__(1024) void scan_local(const int* __restrict__ deg,
    int* __restrict__ loc, int* __restrict__ bsum, int Nn) {
  __shared__ int wsum[16];
  __shared__ int woff[17];
  int b = blockIdx.x, t = threadIdx.x, lane = t & 63, w = t >> 6;
  int i = b * 1024 + t;
  int v = (i < Nn) ? deg[i] : 0;
  int incl = v;
#pragma unroll
  for (int o = 1; o < 64; o <<= 1) { int x = __shfl_up(incl, o); if (lane >= o) incl += x; }
  if (lane == 63) wsum[w] = incl;
  __syncthreads();
  if (t == 0) {
    int r = 0;
#pragma unroll
    for (int j = 0; j < 16; ++j) { woff[j] = r; r += wsum[j]; }
    bsum[b] = r;
  }
  __syncthreads();
  if (i < Nn) loc[i] = woff[w] + incl - v;
}

// add scanned block bases; emit offs + cursor; offs[Nn] = total
__global__ __launch_bounds__(1024) void scan_finish(const int* __restrict__ loc,
    const int* __restrict__ bsum, int* __restrict__ offs, int* __restrict__ cursor,
    int Nn, int nb) {
  __shared__ int boff[65];
  int b = blockIdx.x, t = threadIdx.x;
  if (t < 64) {
    int v = (t < nb) ? bsum[t] : 0;
    int incl = v;
#pragma unroll
    for (int o = 1; o < 64; o <<= 1) { int x = __shfl_up(incl, o); if (t >= o) incl += x; }
    boff[t + 1] = incl;
    if (t == 0) boff[0] = 0;
  }
  __syncthreads();
  int base = boff[b];
  int i = b * 1024 + t;
  if (i < Nn) { int o = loc[i] + base; offs[i] = o; cursor[i] = o; }
  if (b == 0 && t == 0) offs[Nn] = boff[nb];
}

__global__ __launch_bounds__(256) void fill_csr(const int* __restrict__ src,
    const int* __restrict__ dst, int* __restrict__ cursor,
    int* __restrict__ csr, int E) {
  int i = blockIdx.x * 256 + threadIdx.x;
  if (i < E) {
    int d = dst[i];
    int pos = atomicAdd(&cursor[d], 1);
    csr[pos] = src[i];
  }
}

// --------- prep: W0t/W1t/W2t (bf16, transposed) + u = W @ a_{s,d} vectors --------

__global__ __launch_bounds__(256) void prep_kernel(
    const float* __restrict__ W0, const float* __restrict__ W1, const float* __restrict__ W2,
    const float* __restrict__ a0s, const float* __restrict__ a0d,
    const float* __restrict__ a1s, const float* __restrict__ a1d,
    const float* __restrict__ a2s, const float* __restrict__ a2d,
    unsigned short* __restrict__ W0t, unsigned short* __restrict__ W1t,
    unsigned short* __restrict__ W2t,
    float* __restrict__ u0s, float* __restrict__ u0d,
    float* __restrict__ u1s, float* __restrict__ u1d,
    float* __restrict__ u2s, float* __restrict__ u2d) {
  int b = blockIdx.x, t = threadIdx.x;
  if (b < 64) {                       // W0t
    int idx = b * 256 + t; int c = idx >> 7, k = idx & 127;
    W0t[idx] = (unsigned short)bf16rne(W0[k * 128 + c]);
  } else if (b < 128) {               // W1t
    int idx = (b - 64) * 256 + t; int c = idx >> 7, k = idx & 127;
    W1t[idx] = (unsigned short)bf16rne(W1[k * 128 + c]);
  } else if (b < 144) {               // W2t (32 x 128)
    int idx = (b - 128) * 256 + t; int c = idx >> 7, k = idx & 127;
    W2t[idx] = (unsigned short)bf16rne(W2[k * 32 + c]);
  } else if (b == 144) {              // u0
    for (int it = 0; it < 4; ++it) {
      int idx = it * 256 + t;         // 0..1023
      int k = idx >> 3, rem = idx & 7, h = rem >> 1, sd = rem & 1;
      const float* av = sd ? a0d : a0s;
      float s = 0.f;
      for (int o = 0; o < 32; ++o) s += W0[k * 128 + h * 32 + o] * av[h * 32 + o];
      (sd ? u0d : u0s)[k * 4 + h] = s;
    }
  } else if (b == 145) {              // u1
    for (int it = 0; it < 4; ++it) {
      int idx = it * 256 + t;
      int k = idx >> 3, rem = idx & 7, h = rem >> 1, sd = rem & 1;
      const float* av = sd ? a1d : a1s;
      float s = 0.f;
      for (int o = 0; o < 32; ++o) s += W1[k * 128 + h * 32 + o] * av[h * 32 + o];
      (sd ? u1d : u1s)[k * 4 + h] = s;
    }
  } else {                            // u2 (256 outputs)
    int k = t >> 1, sd = t & 1;
    const float* av = sd ? a2d : a2s;
    float s = 0.f;
    for (int o = 0; o < 32; ++o) s += W2[k * 32 + o] * av[o];
    (sd ? u2d : u2s)[k] = s;
  }
}

// --------- xprep: x(f32) -> xbf(bf16) + es0/ed0 = x . u0 (one wave per node) -----

__global__ __launch_bounds__(256) void xprep_kernel(const float* __restrict__ x,
    unsigned* __restrict__ xbf, const float* __restrict__ u0s,
    const float* __restrict__ u0d, float* __restrict__ es, float* __restrict__ ed,
    int Nn) {
  int n = blockIdx.x * 4 + (threadIdx.x >> 6);
  if (n >= Nn) return;
  int l = threadIdx.x & 63;
  int c0 = 2 * l;
  float2 v = *(const float2*)&x[(size_t)n * 128 + c0];
  xbf[(size_t)n * 64 + l] = bf16rne(v.x) | (bf16rne(v.y) << 16);
  float ps[4], pd[4];
#pragma unroll
  for (int h = 0; h < 4; ++h) {
    ps[h] = v.x * u0s[c0 * 4 + h] + v.y * u0s[(c0 + 1) * 4 + h];
    pd[h] = v.x * u0d[c0 * 4 + h] + v.y * u0d[(c0 + 1) * 4 + h];
  }
#pragma unroll
  for (int h = 0; h < 4; ++h)
#pragma unroll
    for (int o = 32; o; o >>= 1) { ps[h] += __shfl_xor(ps[h], o); pd[h] += __shfl_xor(pd[h], o); }
  if (l == 0) {
#pragma unroll
    for (int h = 0; h < 4; ++h) { es[n * 4 + h] = ps[h]; ed[n * 4 + h] = pd[h]; }
  }
}

// --- MFMA GEMM: H(N x NC, fp8) = A(N x 128, bf16) @ W(128 x NC, bf16) -----------

template <int NC>
__global__ __launch_bounds__(256) void gemm_mfma(const unsigned short* __restrict__ Abf,
    const unsigned short* __restrict__ Wt, unsigned char* __restrict__ Hfp,
    int Nrows) {
  constexpr int NT = NC / 16;
  __shared__ unsigned short lw[NC][136];
  int tid = threadIdx.x;
  for (int idx = tid; idx < NC * 16; idx += 256) {
    int c = idx >> 4, k0 = (idx & 15) * 8;
    *(uint4*)&lw[c][k0] = *(const uint4*)&Wt[c * 128 + k0];
  }
  __syncthreads();
  int w = tid >> 6, l = tid & 63;
  int g = l >> 4, i = l & 15;
  int rbase = blockIdx.x * 64 + w * 16;
  int arow = rbase + i; arow = arow < Nrows ? arow : Nrows - 1;
  bf16x8 a[4];
#pragma unroll
  for (int kk = 0; kk < 4; ++kk)
    a[kk] = *(const bf16x8*)&Abf[(size_t)arow * 128 + kk * 32 + g * 8];
  f32x4 acc[NT];
#pragma unroll
  for (int t = 0; t < NT; ++t) acc[t] = (f32x4){0.f, 0.f, 0.f, 0.f};
#pragma unroll
  for (int kk = 0; kk < 4; ++kk) {
#pragma unroll
    for (int t = 0; t < NT; ++t) {
      bf16x8 b = *(const bf16x8*)&lw[t * 16 + i][kk * 32 + g * 8];
      acc[t] = __builtin_amdgcn_mfma_f32_16x16x32_bf16(a[kk], b, acc[t], 0, 0, 0);
    }
  }
  int crow0 = rbase + g * 4;
#pragma unroll
  for (int t = 0; t < NT; ++t)
#pragma unroll
    for (int r = 0; r < 4; ++r) {
      int row = crow0 + r;
      if (row < Nrows)
        Hfp[(size_t)row * NC + t * 16 + i] = fp8enc(acc[t][r]);
    }
}

// --- GAT aggregation (HH=128, 4 heads): 16 lanes/node, 4 nodes/wave, fp8 h ---
// Lane q owns channels [8q,8q+8) = one uint2 of fp8. HW cvt decode (4 ops/edge).

template <bool RES, bool WRITE_F32, int NEXT_NH>
__global__ __launch_bounds__(256) void gat_agg128(const uint2* __restrict__ hfp,
    const float* __restrict__ es, const float* __restrict__ ed,
    const int* __restrict__ offs, const int* __restrict__ csr,
    const float* __restrict__ bias, const float* __restrict__ gamma,
    const float* __restrict__ beta, const float* __restrict__ resid,
    float* __restrict__ out_f32, uint4* __restrict__ out_bf,
    const float* __restrict__ uns, const float* __restrict__ und,
    float* __restrict__ es_next, float* __restrict__ ed_next, int Nn) {
  constexpr int CHK = 16;
  int tid = threadIdx.x;
  int l = tid & 63;
  int q = l & 15;
  int n = blockIdx.x * 16 + (tid >> 6) * 4 + (l >> 4);
  if (n >= Nn) return;
  int hh = q >> 2;
  unsigned c0 = q * 8;
  float edn = ed[n * 4 + hh];
  float e0 = es[n * 4 + hh] + edn;   // self loop; softmax shift-invariant
  e0 = e0 > 0.f ? e0 : 0.2f * e0;
  float w0 = __expf(e0);
  float den = w0;
  float acc[8];
  {
    uint2 u = hfp[(unsigned)n * 16 + q];
    f32x2 p0 = __builtin_amdgcn_cvt_pk_f32_fp8(u.x, false);
    f32x2 p1 = __builtin_amdgcn_cvt_pk_f32_fp8(u.x, true);
    f32x2 p2 = __builtin_amdgcn_cvt_pk_f32_fp8(u.y, false);
    f32x2 p3 = __builtin_amdgcn_cvt_pk_f32_fp8(u.y, true);
    acc[0] = w0 * p0.x; acc[1] = w0 * p0.y;
    acc[2] = w0 * p1.x; acc[3] = w0 * p1.y;
    acc[4] = w0 * p2.x; acc[5] = w0 * p2.y;
    acc[6] = w0 * p3.x; acc[7] = w0 * p3.y;
  }
  int beg = offs[n], end = offs[n + 1];
  for (int base = beg; base < end; base += CHK) {
    int cnt = end - base;   // >=1
    int s[CHK];
#pragma unroll
    for (int j = 0; j < CHK; ++j) s[j] = (j < cnt) ? csr[base + j] : n;
    uint2 hv[CHK];
#pragma unroll
    for (int j = 0; j < CHK; ++j) hv[j] = hfp[(unsigned)s[j] * 16 + q];
    float w[CHK];
#pragma unroll
    for (int j = 0; j < CHK; ++j) {
      float e = es[s[j] * 4 + hh] + edn;
      e = e > 0.f ? e : 0.2f * e;
      w[j] = (j < cnt) ? __expf(e) : 0.f;
    }
#pragma unroll
    for (int j = 0; j < CHK; ++j) {
      f32x2 p0 = __builtin_amdgcn_cvt_pk_f32_fp8(hv[j].x, false);
      f32x2 p1 = __builtin_amdgcn_cvt_pk_f32_fp8(hv[j].x, true);
      f32x2 p2 = __builtin_amdgcn_cvt_pk_f32_fp8(hv[j].y, false);
      f32x2 p3 = __builtin_amdgcn_cvt_pk_f32_fp8(hv[j].y, true);
      den += w[j];
      acc[0] += w[j] * p0.x; acc[1] += w[j] * p0.y;
      acc[2] += w[j] * p1.x; acc[3] += w[j] * p1.y;
      acc[4] += w[j] * p2.x; acc[5] += w[j] * p2.y;
      acc[6] += w[j] * p3.x; acc[7] += w[j] * p3.y;
    }
  }
  float inv = 1.0f / (den + 1e-16f);
  f32x4 bi0 = *(const f32x4*)&bias[c0],  bi1 = *(const f32x4*)&bias[c0 + 4];
  f32x4 ga0 = *(const f32x4*)&gamma[c0], ga1 = *(const f32x4*)&gamma[c0 + 4];
  f32x4 be0 = *(const f32x4*)&beta[c0],  be1 = *(const f32x4*)&beta[c0 + 4];
  f32x4 r0 = (f32x4){0.f,0.f,0.f,0.f}, r1 = r0;
  if (RES) {
    r0 = *(const f32x4*)&resid[(size_t)n * 128 + c0];
    r1 = *(const f32x4*)&resid[(size_t)n * 128 + c0 + 4];
  }
  float o[8];
#pragma unroll
  for (int k = 0; k < 8; ++k) {
    float bi = k < 4 ? bi0[k] : bi1[k - 4];
    float ga = k < 4 ? ga0[k] : ga1[k - 4];
    float be = k < 4 ? be0[k] : be1[k - 4];
    float rv = k < 4 ? r0[k] : r1[k - 4];
    float v = acc[k] * inv + bi;
    if (RES) v += rv;
    v = ga * v * BN_INV + be;
    o[k] = v > 0.f ? v : __expf(v) - 1.f;
  }
  if (WRITE_F32) {
    f32x4 f0 = {o[0], o[1], o[2], o[3]}, f1 = {o[4], o[5], o[6], o[7]};
    *(f32x4*)&out_f32[(size_t)n * 128 + c0] = f0;
    *(f32x4*)&out_f32[(size_t)n * 128 + c0 + 4] = f1;
  }
  uint4 p;
  p.x = bf16rne(o[0]) | (bf16rne(o[1]) << 16);
  p.y = bf16rne(o[2]) | (bf16rne(o[3]) << 16);
  p.z = bf16rne(o[4]) | (bf16rne(o[5]) << 16);
  p.w = bf16rne(o[6]) | (bf16rne(o[7]) << 16);
  out_bf[(unsigned)n * 16 + q] = p;
  // next-layer attention coefficients: es_next = act . u  (16-lane reduce)
  if (NEXT_NH == 4) {
    const f32x4* uns4 = (const f32x4*)uns;
    const f32x4* und4 = (const f32x4*)und;
    f32x4 ps = (f32x4){0.f,0.f,0.f,0.f}, pd = ps;
#pragma unroll
    for (int k = 0; k < 8; ++k) {
      f32x4 us = uns4[c0 + k], ud = und4[c0 + k];
#pragma unroll
      for (int h = 0; h < 4; ++h) { ps[h] += o[k] * us[h]; pd[h] += o[k] * ud[h]; }
    }
#pragma unroll
    for (int h = 0; h < 4; ++h)
#pragma unroll
      for (int m = 1; m < 16; m <<= 1) {
        ps[h] += __shfl_xor(ps[h], m);
        pd[h] += __shfl_xor(pd[h], m);
      }
    if (q == 0) {
#pragma unroll
      for (int h = 0; h < 4; ++h) {
        es_next[n * 4 + h] = ps[h];
        ed_next[n * 4 + h] = pd[h];
      }
    }
  } else {
    float ps = 0.f, pd = 0.f;
#pragma unroll
    for (int k = 0; k < 8; ++k) { ps += o[k] * uns[c0 + k]; pd += o[k] * und[c0 + k]; }
#pragma unroll
    for (int m = 1; m < 16; m <<= 1) { ps += __shfl_xor(ps, m); pd += __shfl_xor(pd, m); }
    if (q == 0) { es_next[n] = ps; ed_next[n] = pd; }
  }
}

// --- layer-2 aggregation (H=1, O=32): 16 lanes/node (2 ch/lane), fp8 h ---

__global__ __launch_bounds__(256) void gat_agg32(const unsigned short* __restrict__ hfp,
    const float* __restrict__ es, const float* __restrict__ ed,
    const int* __restrict__ offs, const int* __restrict__ csr,
    const float* __restrict__ bias, float* __restrict__ h2, int Nn) {
  constexpr int CHK = 16;
  int tid = threadIdx.x;
  int l = tid & 63;
  int q = l & 15;
  int n = blockIdx.x * 16 + (tid >> 6) * 4 + (l >> 4);
  if (n >= Nn) return;
  float edn = ed[n];
  float e0 = es[n] + edn;
  e0 = e0 > 0.f ? e0 : 0.2f * e0;
  float w0 = __expf(e0);
  float den = w0;
  float accx, accy;
  {
    f32x2 p = __builtin_amdgcn_cvt_pk_f32_fp8((unsigned)hfp[(unsigned)n * 16 + q], false);
    accx = w0 * p.x; accy = w0 * p.y;
  }
  int beg = offs[n], end = offs[n + 1];
  for (int base = beg; base < end; base += CHK) {
    int cnt = end - base;
    int s[CHK];
#pragma unroll
    for (int j = 0; j < CHK; ++j) s[j] = (j < cnt) ? csr[base + j] : n;
    unsigned short u[CHK];
#pragma unroll
    for (int j = 0; j < CHK; ++j) u[j] = hfp[(unsigned)s[j] * 16 + q];
    float w[CHK];
#pragma unroll
    for (int j = 0; j < CHK; ++j) {
      float e = es[s[j]] + edn;
      e = e > 0.f ? e : 0.2f * e;
      w[j] = (j < cnt) ? __expf(e) : 0.f;
    }
#pragma unroll
    for (int j = 0; j < CHK; ++j) {
      f32x2 p = __builtin_amdgcn_cvt_pk_f32_fp8((unsigned)u[j], false);
      den += w[j];
      accx += w[j] * p.x;
      accy += w[j] * p.y;
    }
  }
  float inv = 1.0f / (den + 1e-16f);
  float2 bi = *(const float2*)&bias[2 * q];
  float2 o;
  o.x = accx * inv + bi.x;
  o.y = accy * inv + bi.y;
  *(float2*)&h2[(size_t)n * 32 + 2 * q] = o;
}

// -------- head: mean-pool (sorted-batch range), conv1d x2, MLP, log_softmax ------

__global__ __launch_bounds__(256) void head_kernel(const float* __restrict__ h2,
    const int* __restrict__ batch,
    const float* __restrict__ c0w, const float* __restrict__ c0b,
    const float* __restrict__ cg0, const float* __restrict__ cb0,
    const float* __restrict__ c1w, const float* __restrict__ c1b,
    const float* __restrict__ l1w, const float* __restrict__ l1b,
    const float* __restrict__ l2w, const float* __restrict__ l2b,
    float* __restrict__ out) {
  int b = blockIdx.x;
  int t = threadIdx.x;
  __shared__ float sums[8][32];
  __shared__ float pooled[32];
  __shared__ float z1[32][32];
  __shared__ float z2[16][32];
  __shared__ float emb[16];
  __shared__ float hfc[8];
  __shared__ float logits[10];

  int lo = 0, hi = NNODES;
  while (lo < hi) { int mid = (lo + hi) >> 1; if (batch[mid] < b) lo = mid + 1; else hi = mid; }
  int start = lo;
  lo = 0; hi = NNODES;
  while (lo < hi) { int mid = (lo + hi) >> 1; if (batch[mid] < b + 1) lo = mid + 1; else hi = mid; }
  int end = lo;

  {
    int ch = t & 31, g = t >> 5;
    float s = 0.f;
    for (int i = start + g; i < end; i += 8) s += h2[(size_t)i * 32 + ch];
    sums[g][ch] = s;
  }
  __syncthreads();
  if (t < 32) {
    float s = 0.f;
#pragma unroll
    for (int g = 0; g < 8; ++g) s += sums[g][t];
    float cn = fmaxf((float)(end - start), 1.0f);
    pooled[t] = s / cn;
  }
  __syncthreads();
  for (int i = t; i < 1024; i += 256) {
    int oc = i >> 5, tt = i & 31;
    float a = c0b[oc];
#pragma unroll
    for (int k = 0; k < 5; ++k) {
      int p = tt + k - 2;
      if (p >= 0 && p < 32) a += pooled[p] * c0w[oc * 5 + k];
    }
    a = cg0[oc] * a * BN_INV + cb0[oc];
    z1[oc][tt] = a > 0.f ? a : __expf(a) - 1.f;
  }
  __syncthreads();
  for (int i = t; i < 512; i += 256) {
    int oc = i >> 5, tt = i & 31;
    float a = c1b[oc];
    for (int ic = 0; ic < 32; ++ic) {
      const float* wrow = &c1w[(oc * 32 + ic) * 5];
#pragma unroll
      for (int k = 0; k < 5; ++k) {
        int p = tt + k - 2;
        if (p >= 0 && p < 32) a += z1[ic][p] * wrow[k];
      }
    }
    z2[oc][tt] = a;
  }
  __syncthreads();
  if (t < 16) {
    float s = 0.f;
    for (int i = 0; i < 32; ++i) s += z2[t][i];
    s *= (1.0f / 32.0f);
    emb[t] = s;
    out[640 + b * 16 + t] = s;     // output 1: embed (64 x 16)
  }
  __syncthreads();
  if (t < 8) {
    float a = l1b[t];
    for (int i = 0; i < 16; ++i) a += emb[i] * l1w[i * 8 + t];
    hfc[t] = a > 0.f ? a : __expf(a) - 1.f;
  }
  __syncthreads();
  if (t < 10) {
    float a = l2b[t];
    for (int j = 0; j < 8; ++j) a += hfc[j] * l2w[j * 10 + t];
    logits[t] = a;
  }
  __syncthreads();
  if (t == 0) {
    float m = logits[0];
    for (int k = 1; k < 10; ++k) m = fmaxf(m, logits[k]);
    float s = 0.f;
    for (int k = 0; k < 10; ++k) s += __expf(logits[k] - m);
    float lse = m + logf(s);
    for (int k = 0; k < 10; ++k) out[b * 10 + k] = logits[k] - lse;  // output 0
  }
}

// ---------------- launch ----------------

extern "C" void kernel_launch(void* const* d_in, const int* in_sizes, int n_in,
                              void* d_out, int out_size, void* d_ws, size_t ws_size,
                              hipStream_t stream) {
  const float* x   = (const float*)d_in[0];
  const int* eidx  = (const int*)d_in[1];
  const int* esrc  = eidx;
  const int* edst  = eidx + NEDGES;
  const int* batch = (const int*)d_in[2];
  const float* W0  = (const float*)d_in[3];
  const float* a0s = (const float*)d_in[4];
  const float* a0d = (const float*)d_in[5];
  const float* b0  = (const float*)d_in[6];
  const float* W1  = (const float*)d_in[7];
  const float* a1s = (const float*)d_in[8];
  const float* a1d = (const float*)d_in[9];
  const float* b1  = (const float*)d_in[10];
  const float* W2  = (const float*)d_in[11];
  const float* a2s = (const float*)d_in[12];
  const float* a2d = (const float*)d_in[13];
  const float* b2  = (const float*)d_in[14];
  const float* g0  = (const float*)d_in[15];
  const float* be0 = (const float*)d_in[16];
  const float* g1  = (const float*)d_in[17];
  const float* be1 = (const float*)d_in[18];
  const float* c0w = (const float*)d_in[19];
  const float* c0b = (const float*)d_in[20];
  const float* cg0 = (const float*)d_in[21];
  const float* cb0 = (const float*)d_in[22];
  const float* c1w = (const float*)d_in[23];
  const float* c1b = (const float*)d_in[24];
  const float* l1w = (const float*)d_in[25];
  const float* l1b = (const float*)d_in[26];
  const float* l2w = (const float*)d_in[27];
  const float* l2b = (const float*)d_in[28];

  char* ws = (char*)d_ws;
  int*            deg    = (int*)(ws + 0);
  int*            cursor = (int*)(ws + 208448);
  int*            offs   = (int*)(ws + 408448);
  float*          esA    = (float*)(ws + 608512);
  float*          edA    = (float*)(ws + 1408512);
  float*          esB    = (float*)(ws + 2208512);
  float*          edB    = (float*)(ws + 3008512);
  int*            csr    = (int*)(ws + 3808512);
  unsigned*       Abf    = (unsigned*)(ws + 7008512);    // N x 64 uints (bf16 pairs)
  unsigned char*  hfp    = (unsigned char*)(ws + 19808512);  // N x 128 fp8 (l2: N x 32)
  float*          act0   = (float*)(ws + 32608512);      // N x 128 f32 (h2 reuse)
  unsigned short* W0t    = (unsigned short*)(ws + 58208512);
  unsigned short* W1t    = (unsigned short*)(ws + 58241280);
  unsigned short* W2t    = (unsigned short*)(ws + 58274048);
  float*          u0s    = (float*)(ws + 58282240);
  float*          u0d    = (float*)(ws + 58284288);
  float*          u1s    = (float*)(ws + 58286336);
  float*          u1d    = (float*)(ws + 58288384);
  float*          u2s    = (float*)(ws + 58290432);
  float*          u2d    = (float*)(ws + 58290944);
  int*            sloc   = (int*)(ws + 58291456);        // 50000 i32 scan scratch
  int*            sbsum  = (int*)(ws + 58491456);        // 49 i32 block sums
  float*          h2     = act0;
  float*          out    = (float*)d_out;

  hipMemsetAsync(d_ws, 0, 200000, stream);   // deg = 0

  count_deg<<<(NEDGES + 255) / 256, 256, 0, stream>>>(edst, deg, NEDGES);
  scan_local<<<SCAN_NB, 1024, 0, stream>>>(deg, sloc, sbsum, NNODES);
  scan_finish<<<SCAN_NB, 1024, 0, stream>>>(sloc, sbsum, offs, cursor, NNODES, SCAN_NB);
  fill_csr<<<(NEDGES + 255) / 256, 256, 0, stream>>>(esrc, edst, cursor, csr, NEDGES);

  prep_kernel<<<147, 256, 0, stream>>>(W0, W1, W2, a0s, a0d, a1s, a1d, a2s, a2d,
                                       W0t, W1t, W2t, u0s, u0d, u1s, u1d, u2s, u2d);
  xprep_kernel<<<NNODES / 4, 256, 0, stream>>>(x, Abf, u0s, u0d, esA, edA, NNODES);

  const int ggrid = (NNODES + 63) / 64;
  const int agrid = (NNODES + 15) / 16;

  // --- layer 0 ---
  gemm_mfma<128><<<ggrid, 256, 0, stream>>>((const unsigned short*)Abf, W0t,
                                            hfp, NNODES);
  gat_agg128<false, true, 4><<<agrid, 256, 0, stream>>>(
      (const uint2*)hfp, esA, edA, offs, csr, b0, g0, be0, nullptr,
      act0, (uint4*)Abf, u1s, u1d, esB, edB, NNODES);

  // --- layer 1 (residual) ---
  gemm_mfma<128><<<ggrid, 256, 0, stream>>>((const unsigned short*)Abf, W1t,
                                            hfp, NNODES);
  gat_agg128<true, false, 1><<<agrid, 256, 0, stream>>>(
      (const uint2*)hfp, esB, edB, offs, csr, b1, g1, be1, act0,
      nullptr, (uint4*)Abf, u2s, u2d, esA, edA, NNODES);

  // --- layer 2 (H=1, O=32) ---
  gemm_mfma<32><<<ggrid, 256, 0, stream>>>((const unsigned short*)Abf, W2t,
                                           hfp, NNODES);
  gat_agg32<<<agrid, 256, 0, stream>>>((const unsigned short*)hfp,
                                       esA, edA, offs, csr, b2, h2, NNODES);

  // --- head (pool fused) ---
  head_kernel<<<64, 256, 0, stream>>>(h2, batch, c0w, c0b, cg0, cb0,
                                      c1w, c1b, l1w, l1b, l2w, l2b, out);
}